// Round 1
// baseline (1110.063 us; speedup 1.0000x reference)
//
#include <hip/hip_runtime.h>
#include <math.h>

// Problem constants
constexpr int D      = 512;
constexpr int NH     = 8;
constexpr int HD     = 64;     // head dim == wave size
constexpr int WIN    = 128;
constexpr int DFF    = 2048;
constexpr int SEQ    = 4096;
constexpr float LN_EPS = 1e-5f;

// ---------------------------------------------------------------------------
// Generic tiled fp32 GEMM: C[M,N] = A[M,K] @ B[K,N] + bias[N], optional ReLU.
// 64x64 tile, BK=16, 256 threads, 4x4 per thread.
// ---------------------------------------------------------------------------
template <bool RELU>
__global__ __launch_bounds__(256) void gemm_bias(
    const float* __restrict__ A, const float* __restrict__ B,
    const float* __restrict__ bias, float* __restrict__ C,
    int M, int N, int K)
{
    __shared__ float As[16][65];  // [k][m], padded to kill store conflicts
    __shared__ float Bs[16][64];  // [k][n]

    const int tid = threadIdx.x;
    const int tx = tid & 15;        // 16 cols of threads
    const int ty = tid >> 4;        // 16 rows of threads
    const int m0 = blockIdx.y * 64;
    const int n0 = blockIdx.x * 64;

    float acc[4][4] = {};

    for (int k0 = 0; k0 < K; k0 += 16) {
        // Load A tile (64 rows x 16 k) transposed into As[k][m]
        #pragma unroll
        for (int r = 0; r < 4; ++r) {
            int idx = tid + r * 256;          // 0..1023
            int row = idx >> 4;               // 0..63
            int col = idx & 15;               // 0..15
            As[col][row] = A[(size_t)(m0 + row) * K + (k0 + col)];
        }
        // Load B tile (16 k x 64 n) into Bs[k][n]
        #pragma unroll
        for (int r = 0; r < 4; ++r) {
            int idx = tid + r * 256;
            int row = idx >> 6;               // 0..15
            int col = idx & 63;               // 0..63
            Bs[row][col] = B[(size_t)(k0 + row) * N + (n0 + col)];
        }
        __syncthreads();

        #pragma unroll
        for (int k = 0; k < 16; ++k) {
            float a[4], b[4];
            #pragma unroll
            for (int i = 0; i < 4; ++i) a[i] = As[k][ty * 4 + i];
            #pragma unroll
            for (int j = 0; j < 4; ++j) b[j] = Bs[k][tx * 4 + j];
            #pragma unroll
            for (int i = 0; i < 4; ++i)
                #pragma unroll
                for (int j = 0; j < 4; ++j)
                    acc[i][j] = fmaf(a[i], b[j], acc[i][j]);
        }
        __syncthreads();
    }

    #pragma unroll
    for (int i = 0; i < 4; ++i) {
        int row = m0 + ty * 4 + i;
        #pragma unroll
        for (int j = 0; j < 4; ++j) {
            int col = n0 + tx * 4 + j;
            float v = acc[i][j] + bias[col];
            if (RELU) v = fmaxf(v, 0.0f);
            C[(size_t)row * N + col] = v;
        }
    }
}

// ---------------------------------------------------------------------------
// Windowed attention, online softmax. One wave (64 lanes) per (head, query).
// qkv layout: [SEQ][3*D]; q at h*64, k at D + h*64, v at 2D + h*64.
// Writes o[SEQ][D] with heads concatenated (matches reference reshape).
// ---------------------------------------------------------------------------
__global__ __launch_bounds__(256) void attn_window(
    const float* __restrict__ qkv, float* __restrict__ o)
{
    const int wave = threadIdx.x >> 6;
    const int lane = threadIdx.x & 63;
    const int i = blockIdx.x * 4 + wave;   // query index
    const int h = blockIdx.y;
    const float scale = 0.044194173824159216f;  // 1/sqrt(512) (d_model!)

    const float q = qkv[(size_t)i * (3 * D) + h * HD + lane];

    const int jlo = (i - WIN > 0) ? i - WIN : 0;
    const int jhi = (i + WIN < SEQ - 1) ? i + WIN : SEQ - 1;

    float m = -INFINITY, l = 0.0f, acc = 0.0f;
    for (int j = jlo; j <= jhi; ++j) {
        const float* base = qkv + (size_t)j * (3 * D) + h * HD;
        float kv = base[D + lane];
        float vv = base[2 * D + lane];
        float prod = q * kv;
        #pragma unroll
        for (int off = 32; off; off >>= 1) prod += __shfl_xor(prod, off, 64);
        float s = prod * scale;
        float mnew = fmaxf(m, s);
        float corr = __expf(m - mnew);   // first iter: exp(-inf)=0
        float p = __expf(s - mnew);
        l   = l * corr + p;
        acc = acc * corr + p * vv;
        m = mnew;
    }
    o[(size_t)i * D + h * HD + lane] = acc / l;
}

// ---------------------------------------------------------------------------
// out[row] = LayerNorm(a[row] + b[row]) * g + beta.  One wave per 512-el row.
// ---------------------------------------------------------------------------
__global__ __launch_bounds__(256) void add_ln(
    const float* __restrict__ a, const float* __restrict__ b,
    const float* __restrict__ g, const float* __restrict__ beta,
    float* __restrict__ out)
{
    const int wave = threadIdx.x >> 6;
    const int lane = threadIdx.x & 63;
    const int row = blockIdx.x * 4 + wave;

    const float* pa = a + (size_t)row * D;
    const float* pb = b + (size_t)row * D;

    float v[8];
    float sum = 0.0f, sumsq = 0.0f;
    #pragma unroll
    for (int e = 0; e < 8; ++e) {
        float z = pa[lane + e * 64] + pb[lane + e * 64];
        v[e] = z;
        sum += z;
        sumsq += z * z;
    }
    #pragma unroll
    for (int off = 32; off; off >>= 1) {
        sum   += __shfl_xor(sum, off, 64);
        sumsq += __shfl_xor(sumsq, off, 64);
    }
    const float mu   = sum * (1.0f / D);
    const float var  = sumsq * (1.0f / D) - mu * mu;
    const float rstd = rsqrtf(var + LN_EPS);

    float* po = out + (size_t)row * D;
    #pragma unroll
    for (int e = 0; e < 8; ++e) {
        int c = lane + e * 64;
        po[c] = (v[e] - mu) * rstd * g[c] + beta[c];
    }
}

// ---------------------------------------------------------------------------
extern "C" void kernel_launch(void* const* d_in, const int* in_sizes, int n_in,
                              void* d_out, int out_size, void* d_ws, size_t ws_size,
                              hipStream_t stream)
{
    const float* x      = (const float*)d_in[0];
    const float* qkv_w  = (const float*)d_in[1];
    const float* qkv_b  = (const float*)d_in[2];
    const float* out_w  = (const float*)d_in[3];
    const float* out_b  = (const float*)d_in[4];
    const float* ln1_g  = (const float*)d_in[5];
    const float* ln1_b  = (const float*)d_in[6];
    const float* w1     = (const float*)d_in[7];
    const float* b1     = (const float*)d_in[8];
    const float* w2     = (const float*)d_in[9];
    const float* b2     = (const float*)d_in[10];
    const float* ln2_g  = (const float*)d_in[11];
    const float* ln2_b  = (const float*)d_in[12];
    float* out = (float*)d_out;

    // Workspace layout (floats)
    float* ws = (float*)d_ws;
    float* qkv      = ws;                       // SEQ*3D   = 6291456
    float* o_buf    = qkv      + (size_t)SEQ * 3 * D;   // SEQ*D
    float* attn_out = o_buf    + (size_t)SEQ * D;       // SEQ*D
    float* x1       = attn_out + (size_t)SEQ * D;       // SEQ*D
    float* ff1      = x1       + (size_t)SEQ * D;       // SEQ*DFF
    float* ff2      = ff1      + (size_t)SEQ * DFF;     // SEQ*D

    // 1) qkv = x @ qkv_w + qkv_b           [4096, 1536]
    gemm_bias<false><<<dim3((3 * D) / 64, SEQ / 64), 256, 0, stream>>>(
        x, qkv_w, qkv_b, qkv, SEQ, 3 * D, D);

    // 2) windowed attention -> o           [4096, 512]
    attn_window<<<dim3(SEQ / 4, NH), 256, 0, stream>>>(qkv, o_buf);

    // 3) attn_out = o @ out_w + out_b      [4096, 512]
    gemm_bias<false><<<dim3(D / 64, SEQ / 64), 256, 0, stream>>>(
        o_buf, out_w, out_b, attn_out, SEQ, D, D);

    // 4) x1 = LN(x + attn_out)
    add_ln<<<SEQ / 4, 256, 0, stream>>>(x, attn_out, ln1_g, ln1_b, x1);

    // 5) ff1 = relu(x1 @ w1 + b1)          [4096, 2048]
    gemm_bias<true><<<dim3(DFF / 64, SEQ / 64), 256, 0, stream>>>(
        x1, w1, b1, ff1, SEQ, DFF, D);

    // 6) ff2 = ff1 @ w2 + b2               [4096, 512]
    gemm_bias<false><<<dim3(D / 64, SEQ / 64), 256, 0, stream>>>(
        ff1, w2, b2, ff2, SEQ, D, DFF);

    // 7) out = LN(x1 + ff2)
    add_ln<<<SEQ / 4, 256, 0, stream>>>(x1, ff2, ln2_g, ln2_b, out);
}

// Round 2
// 776.438 us; speedup vs baseline: 1.4297x; 1.4297x over previous
//
#include <hip/hip_runtime.h>
#include <math.h>

// Problem constants
constexpr int D      = 512;
constexpr int NH     = 8;
constexpr int HD     = 64;     // head dim == wave size
constexpr int WIN    = 128;
constexpr int DFF    = 2048;
constexpr int SEQ    = 4096;
constexpr float LN_EPS = 1e-5f;

// ---------------------------------------------------------------------------
// Generic tiled fp32 GEMM: C[M,N] = A[M,K] @ B[K,N] + bias[N], optional ReLU.
// 64x64 tile, BK=16, 256 threads, 4x4 per thread.
// ---------------------------------------------------------------------------
template <bool RELU>
__global__ __launch_bounds__(256) void gemm_bias(
    const float* __restrict__ A, const float* __restrict__ B,
    const float* __restrict__ bias, float* __restrict__ C,
    int M, int N, int K)
{
    __shared__ float As[16][65];  // [k][m], padded
    __shared__ float Bs[16][64];  // [k][n]

    const int tid = threadIdx.x;
    const int tx = tid & 15;
    const int ty = tid >> 4;
    const int m0 = blockIdx.y * 64;
    const int n0 = blockIdx.x * 64;

    float acc[4][4] = {};

    for (int k0 = 0; k0 < K; k0 += 16) {
        #pragma unroll
        for (int r = 0; r < 4; ++r) {
            int idx = tid + r * 256;
            int row = idx >> 4;
            int col = idx & 15;
            As[col][row] = A[(size_t)(m0 + row) * K + (k0 + col)];
        }
        #pragma unroll
        for (int r = 0; r < 4; ++r) {
            int idx = tid + r * 256;
            int row = idx >> 6;
            int col = idx & 63;
            Bs[row][col] = B[(size_t)(k0 + row) * N + (n0 + col)];
        }
        __syncthreads();

        #pragma unroll
        for (int k = 0; k < 16; ++k) {
            float a[4], b[4];
            #pragma unroll
            for (int i = 0; i < 4; ++i) a[i] = As[k][ty * 4 + i];
            #pragma unroll
            for (int j = 0; j < 4; ++j) b[j] = Bs[k][tx * 4 + j];
            #pragma unroll
            for (int i = 0; i < 4; ++i)
                #pragma unroll
                for (int j = 0; j < 4; ++j)
                    acc[i][j] = fmaf(a[i], b[j], acc[i][j]);
        }
        __syncthreads();
    }

    #pragma unroll
    for (int i = 0; i < 4; ++i) {
        int row = m0 + ty * 4 + i;
        #pragma unroll
        for (int j = 0; j < 4; ++j) {
            int col = n0 + tx * 4 + j;
            float v = acc[i][j] + bias[col];
            if (RELU) v = fmaxf(v, 0.0f);
            C[(size_t)row * N + col] = v;
        }
    }
}

// ---------------------------------------------------------------------------
// Windowed attention, lane = query. Block = 128 threads (2 waves) per
// (64-query tile, head). Wave w processes key-chunks c%2==w into its own LDS
// buffer (no barriers in the loop); softmax is a pure sum (p=exp(s), scores
// are O(1) so no max-subtraction needed; masked -> p=0 exactly), so the two
// waves' (l, acc) merge by addition at the end.
// qkv layout: [SEQ][3*D]; per row: q | k | v, head h at offset h*64.
// ---------------------------------------------------------------------------
__global__ __launch_bounds__(128) void attn_flash(
    const float* __restrict__ qkv, float* __restrict__ o)
{
    __shared__ float smem[4 * 64 * 64];  // K0 | K1 | V0 | V1, 64 KB

    const int lane = threadIdx.x & 63;
    const int wv   = threadIdx.x >> 6;       // 0 or 1
    const int i0   = blockIdx.x * 64;
    const int h    = blockIdx.y;
    const int i    = i0 + lane;              // this lane's query row
    const float scale = 0.044194173824159216f;  // 1/sqrt(512) (d_model!)

    float* Kbuf = smem + wv * 4096;          // [64][64]
    float* Vbuf = smem + 8192 + wv * 4096;   // [64][64]

    // Q row for this lane: 64 floats in registers
    float4 q4[16];
    const float* qbase = qkv + (size_t)i * (3 * D) + h * HD;
    #pragma unroll
    for (int dq = 0; dq < 16; ++dq) q4[dq] = *(const float4*)(qbase + dq * 4);

    float4 acc4[16];
    #pragma unroll
    for (int dq = 0; dq < 16; ++dq) acc4[dq] = make_float4(0.f, 0.f, 0.f, 0.f);
    float l = 0.0f;

    // Window of this tile: keys [i0-128, i0+63+128] -> 5 chunks of 64
    for (int c = wv; c < 5; c += 2) {
        const int j0 = i0 - WIN + c * 64;
        if (j0 >= SEQ) break;
        if (j0 + 63 < 0) continue;

        // Stage K and V chunk (64 rows x 64 dims) into this wave's buffers.
        #pragma unroll
        for (int it = 0; it < 16; ++it) {
            int idx = it * 64 + lane;
            int row = idx >> 4;              // 0..63
            int qd  = idx & 15;              // 0..15
            int j   = j0 + row;
            int jc  = j < 0 ? 0 : (j >= SEQ ? SEQ - 1 : j);
            const float* base = qkv + (size_t)jc * (3 * D) + h * HD + qd * 4;
            *(float4*)&Kbuf[row * 64 + qd * 4] = *(const float4*)(base + D);
            *(float4*)&Vbuf[row * 64 + qd * 4] = *(const float4*)(base + 2 * D);
        }
        // (intra-wave LDS ordering: ds ops complete in order per wave;
        //  compiler inserts lgkmcnt waits for the RAW dependency)

        for (int jj = 0; jj < 64; ++jj) {
            const int j = j0 + jj;
            float s0 = 0.f, s1 = 0.f, s2 = 0.f, s3 = 0.f;
            #pragma unroll
            for (int dq = 0; dq < 16; ++dq) {
                float4 k4 = *(const float4*)&Kbuf[jj * 64 + dq * 4];
                s0 = fmaf(q4[dq].x, k4.x, s0);
                s1 = fmaf(q4[dq].y, k4.y, s1);
                s2 = fmaf(q4[dq].z, k4.z, s2);
                s3 = fmaf(q4[dq].w, k4.w, s3);
            }
            float s = ((s0 + s1) + (s2 + s3)) * scale;
            bool valid = (j >= 0) && (j < SEQ) && (j >= i - WIN) && (j <= i + WIN);
            s = valid ? s : -1e30f;          // exp(-1e30) underflows to 0
            float p = __expf(s);
            l += p;
            #pragma unroll
            for (int dq = 0; dq < 16; ++dq) {
                float4 v4 = *(const float4*)&Vbuf[jj * 64 + dq * 4];
                acc4[dq].x = fmaf(p, v4.x, acc4[dq].x);
                acc4[dq].y = fmaf(p, v4.y, acc4[dq].y);
                acc4[dq].z = fmaf(p, v4.z, acc4[dq].z);
                acc4[dq].w = fmaf(p, v4.w, acc4[dq].w);
            }
        }
    }

    // Merge the two waves' partial sums. After this barrier all K/V buffers
    // are dead, so reuse them for the exchange (stride 65 -> 2-way banks).
    __syncthreads();
    float* abuf = smem + 4096;   // 64 queries x stride 65 (4160 floats)
    float* lbuf = smem;          // 64 floats
    if (wv == 1) {
        #pragma unroll
        for (int dq = 0; dq < 16; ++dq)
            *(float4*)&abuf[lane * 65 + dq * 4] = acc4[dq];
        lbuf[lane] = l;
    }
    __syncthreads();
    if (wv == 0) {
        l += lbuf[lane];
        const float rl = 1.0f / l;
        float* obase = o + (size_t)i * D + h * HD;
        #pragma unroll
        for (int dq = 0; dq < 16; ++dq) {
            float4 a2 = *(const float4*)&abuf[lane * 65 + dq * 4];
            float4 r;
            r.x = (acc4[dq].x + a2.x) * rl;
            r.y = (acc4[dq].y + a2.y) * rl;
            r.z = (acc4[dq].z + a2.z) * rl;
            r.w = (acc4[dq].w + a2.w) * rl;
            *(float4*)(obase + dq * 4) = r;
        }
    }
}

// ---------------------------------------------------------------------------
// out[row] = LayerNorm(a[row] + b[row]) * g + beta.  One wave per 512-el row.
// ---------------------------------------------------------------------------
__global__ __launch_bounds__(256) void add_ln(
    const float* __restrict__ a, const float* __restrict__ b,
    const float* __restrict__ g, const float* __restrict__ beta,
    float* __restrict__ out)
{
    const int wave = threadIdx.x >> 6;
    const int lane = threadIdx.x & 63;
    const int row = blockIdx.x * 4 + wave;

    const float* pa = a + (size_t)row * D;
    const float* pb = b + (size_t)row * D;

    float v[8];
    float sum = 0.0f, sumsq = 0.0f;
    #pragma unroll
    for (int e = 0; e < 8; ++e) {
        float z = pa[lane + e * 64] + pb[lane + e * 64];
        v[e] = z;
        sum += z;
        sumsq += z * z;
    }
    #pragma unroll
    for (int off = 32; off; off >>= 1) {
        sum   += __shfl_xor(sum, off, 64);
        sumsq += __shfl_xor(sumsq, off, 64);
    }
    const float mu   = sum * (1.0f / D);
    const float var  = sumsq * (1.0f / D) - mu * mu;
    const float rstd = rsqrtf(var + LN_EPS);

    float* po = out + (size_t)row * D;
    #pragma unroll
    for (int e = 0; e < 8; ++e) {
        int c = lane + e * 64;
        po[c] = (v[e] - mu) * rstd * g[c] + beta[c];
    }
}

// ---------------------------------------------------------------------------
extern "C" void kernel_launch(void* const* d_in, const int* in_sizes, int n_in,
                              void* d_out, int out_size, void* d_ws, size_t ws_size,
                              hipStream_t stream)
{
    const float* x      = (const float*)d_in[0];
    const float* qkv_w  = (const float*)d_in[1];
    const float* qkv_b  = (const float*)d_in[2];
    const float* out_w  = (const float*)d_in[3];
    const float* out_b  = (const float*)d_in[4];
    const float* ln1_g  = (const float*)d_in[5];
    const float* ln1_b  = (const float*)d_in[6];
    const float* w1     = (const float*)d_in[7];
    const float* b1     = (const float*)d_in[8];
    const float* w2     = (const float*)d_in[9];
    const float* b2     = (const float*)d_in[10];
    const float* ln2_g  = (const float*)d_in[11];
    const float* ln2_b  = (const float*)d_in[12];
    float* out = (float*)d_out;

    // Workspace layout (floats)
    float* ws = (float*)d_ws;
    float* qkv      = ws;                               // SEQ*3D
    float* o_buf    = qkv      + (size_t)SEQ * 3 * D;   // SEQ*D
    float* attn_out = o_buf    + (size_t)SEQ * D;       // SEQ*D
    float* x1       = attn_out + (size_t)SEQ * D;       // SEQ*D
    float* ff1      = x1       + (size_t)SEQ * D;       // SEQ*DFF
    float* ff2      = ff1      + (size_t)SEQ * DFF;     // SEQ*D

    // 1) qkv = x @ qkv_w + qkv_b           [4096, 1536]
    gemm_bias<false><<<dim3((3 * D) / 64, SEQ / 64), 256, 0, stream>>>(
        x, qkv_w, qkv_b, qkv, SEQ, 3 * D, D);

    // 2) windowed attention -> o           [4096, 512]
    attn_flash<<<dim3(SEQ / 64, NH), 128, 0, stream>>>(qkv, o_buf);

    // 3) attn_out = o @ out_w + out_b      [4096, 512]
    gemm_bias<false><<<dim3(D / 64, SEQ / 64), 256, 0, stream>>>(
        o_buf, out_w, out_b, attn_out, SEQ, D, D);

    // 4) x1 = LN(x + attn_out)
    add_ln<<<SEQ / 4, 256, 0, stream>>>(x, attn_out, ln1_g, ln1_b, x1);

    // 5) ff1 = relu(x1 @ w1 + b1)          [4096, 2048]
    gemm_bias<true><<<dim3(DFF / 64, SEQ / 64), 256, 0, stream>>>(
        x1, w1, b1, ff1, SEQ, DFF, D);

    // 6) ff2 = ff1 @ w2 + b2               [4096, 512]
    gemm_bias<false><<<dim3(D / 64, SEQ / 64), 256, 0, stream>>>(
        ff1, w2, b2, ff2, SEQ, D, DFF);

    // 7) out = LN(x1 + ff2)
    add_ln<<<SEQ / 4, 256, 0, stream>>>(x1, ff2, ln2_g, ln2_b, out);
}

// Round 3
// 362.550 us; speedup vs baseline: 3.0618x; 2.1416x over previous
//
#include <hip/hip_runtime.h>
#include <math.h>

// Problem constants
constexpr int D      = 512;
constexpr int NH     = 8;
constexpr int HD     = 64;
constexpr int WIN    = 128;
constexpr int DFF    = 2048;
constexpr int SEQ    = 4096;
constexpr float LN_EPS = 1e-5f;

typedef float f32x4 __attribute__((ext_vector_type(4)));
typedef __bf16 bf16x8 __attribute__((ext_vector_type(8)));

__device__ __forceinline__ unsigned short f2bf(float f) {
    union { float f; unsigned u; } v; v.f = f;
    unsigned r = v.u + 0x7FFF + ((v.u >> 16) & 1);   // round-to-nearest-even
    return (unsigned short)(r >> 16);
}

__device__ __forceinline__ void gload16(const void* g, void* l) {
    __builtin_amdgcn_global_load_lds(
        (const __attribute__((address_space(1))) unsigned int*)g,
        (__attribute__((address_space(3))) unsigned int*)l,
        16, 0, 0);
}

// ---------------------------------------------------------------------------
// fp32 -> bf16 elementwise (4 elems/thread)
// ---------------------------------------------------------------------------
__global__ __launch_bounds__(256) void f32_to_bf16(
    const float* __restrict__ in, unsigned short* __restrict__ out, int n)
{
    int i = (blockIdx.x * 256 + threadIdx.x) * 4;
    if (i >= n) return;
    float4 v = *(const float4*)(in + i);
    ushort4 u = make_ushort4(f2bf(v.x), f2bf(v.y), f2bf(v.z), f2bf(v.w));
    *(ushort4*)(out + i) = u;
}

// ---------------------------------------------------------------------------
// W [K][N] fp32 -> Wt [N][K] bf16 (32x32 LDS tile transpose)
// block (32,8), grid (N/32, K/32)
// ---------------------------------------------------------------------------
__global__ __launch_bounds__(256) void transpose_bf16(
    const float* __restrict__ W, unsigned short* __restrict__ Wt, int K, int N)
{
    __shared__ float t[32][33];
    const int n0 = blockIdx.x * 32, k0 = blockIdx.y * 32;
    #pragma unroll
    for (int r = 0; r < 4; ++r)
        t[threadIdx.y + r * 8][threadIdx.x] =
            W[(size_t)(k0 + threadIdx.y + r * 8) * N + n0 + threadIdx.x];
    __syncthreads();
    #pragma unroll
    for (int r = 0; r < 4; ++r)
        Wt[(size_t)(n0 + threadIdx.y + r * 8) * K + k0 + threadIdx.x] =
            f2bf(t[threadIdx.x][threadIdx.y + r * 8]);
}

// ---------------------------------------------------------------------------
// MFMA GEMM: C[M,N] = A[M,K](bf16) @ Bt[N,K](bf16)^T + bias, opt ReLU,
// output fp32 or bf16. 128x128 tile, BK=32, 4 waves each 64x64 (4x4 frags of
// 16x16x32). Single-buffer LDS staged with global_load_lds width=16 (m97).
// Requires M%128==0, N%128==0, K%32==0.
// ---------------------------------------------------------------------------
template <bool RELU, bool OUT_BF16>
__global__ __launch_bounds__(256) void gemm_mfma(
    const unsigned short* __restrict__ A,
    const unsigned short* __restrict__ Bt,
    const float* __restrict__ bias,
    void* __restrict__ Cv, int M, int N, int K)
{
    __shared__ __align__(16) char lds[16384];   // A: [0,8K) rows of 64B; B: [8K,16K)

    const int tid  = threadIdx.x;
    const int lane = tid & 63;
    const int wave = tid >> 6;
    const int wr = wave >> 1, wc = wave & 1;
    const int m0 = blockIdx.y * 128, n0 = blockIdx.x * 128;

    f32x4 acc[4][4];
    #pragma unroll
    for (int m = 0; m < 4; ++m)
        #pragma unroll
        for (int n = 0; n < 4; ++n)
            acc[m][n] = f32x4{0.f, 0.f, 0.f, 0.f};

    const int lr = lane & 15, lk = lane >> 4;
    const int aoff = ((wr * 64 + lr) << 6) + (lk << 4);          // bytes
    const int boff = 8192 + ((wc * 64 + lr) << 6) + (lk << 4);

    // staging geometry: linear LDS byte L = r*4096 + tid*16 -> row=L>>6, kbyte=L&63
    const int srow = (tid * 16) >> 6;      // 0..63
    const int skb  = (tid * 16) & 63;      // byte within 64B row

    for (int k0 = 0; k0 < K; k0 += 32) {
        #pragma unroll
        for (int r = 0; r < 2; ++r) {
            int row = srow + r * 64;
            gload16((const char*)A + ((size_t)(m0 + row) * K + k0) * 2 + skb,
                    lds + r * 4096 + tid * 16);
        }
        #pragma unroll
        for (int r = 0; r < 2; ++r) {
            int row = srow + r * 64;
            gload16((const char*)Bt + ((size_t)(n0 + row) * K + k0) * 2 + skb,
                    lds + 8192 + r * 4096 + tid * 16);
        }
        __syncthreads();   // drains vmcnt -> staged data visible

        bf16x8 af[4], bfv[4];
        #pragma unroll
        for (int m = 0; m < 4; ++m)
            af[m] = *(const bf16x8*)(lds + aoff + m * 1024);
        #pragma unroll
        for (int n = 0; n < 4; ++n)
            bfv[n] = *(const bf16x8*)(lds + boff + n * 1024);

        #pragma unroll
        for (int m = 0; m < 4; ++m)
            #pragma unroll
            for (int n = 0; n < 4; ++n)
                acc[m][n] = __builtin_amdgcn_mfma_f32_16x16x32_bf16(
                    af[m], bfv[n], acc[m][n], 0, 0, 0);
        __syncthreads();   // LDS reads done before next stage overwrites
    }

    // Epilogue: D col = lane&15, row = (lane>>4)*4 + j  (per 16x16 frag)
    const int col0 = n0 + wc * 64 + lr;
    const int row0 = m0 + wr * 64 + lk * 4;
    #pragma unroll
    for (int m = 0; m < 4; ++m) {
        #pragma unroll
        for (int n = 0; n < 4; ++n) {
            int col = col0 + n * 16;
            float bv = bias[col];
            #pragma unroll
            for (int j = 0; j < 4; ++j) {
                int row = row0 + m * 16 + j;
                float v = acc[m][n][j] + bv;
                if (RELU) v = fmaxf(v, 0.0f);
                if (OUT_BF16)
                    ((unsigned short*)Cv)[(size_t)row * N + col] = f2bf(v);
                else
                    ((float*)Cv)[(size_t)row * N + col] = v;
            }
        }
    }
}

// ---------------------------------------------------------------------------
// Windowed attention, lane = query (as round 1), output bf16.
// ---------------------------------------------------------------------------
__global__ __launch_bounds__(128) void attn_flash(
    const float* __restrict__ qkv, unsigned short* __restrict__ o)
{
    __shared__ float smem[4 * 64 * 64];

    const int lane = threadIdx.x & 63;
    const int wv   = threadIdx.x >> 6;
    const int i0   = blockIdx.x * 64;
    const int h    = blockIdx.y;
    const int i    = i0 + lane;
    const float scale = 0.044194173824159216f;  // 1/sqrt(512) (d_model!)

    float* Kbuf = smem + wv * 4096;
    float* Vbuf = smem + 8192 + wv * 4096;

    float4 q4[16];
    const float* qbase = qkv + (size_t)i * (3 * D) + h * HD;
    #pragma unroll
    for (int dq = 0; dq < 16; ++dq) q4[dq] = *(const float4*)(qbase + dq * 4);

    float4 acc4[16];
    #pragma unroll
    for (int dq = 0; dq < 16; ++dq) acc4[dq] = make_float4(0.f, 0.f, 0.f, 0.f);
    float l = 0.0f;

    for (int c = wv; c < 5; c += 2) {
        const int j0 = i0 - WIN + c * 64;
        if (j0 >= SEQ) break;
        if (j0 + 63 < 0) continue;

        #pragma unroll
        for (int it = 0; it < 16; ++it) {
            int idx = it * 64 + lane;
            int row = idx >> 4;
            int qd  = idx & 15;
            int j   = j0 + row;
            int jc  = j < 0 ? 0 : (j >= SEQ ? SEQ - 1 : j);
            const float* base = qkv + (size_t)jc * (3 * D) + h * HD + qd * 4;
            *(float4*)&Kbuf[row * 64 + qd * 4] = *(const float4*)(base + D);
            *(float4*)&Vbuf[row * 64 + qd * 4] = *(const float4*)(base + 2 * D);
        }

        for (int jj = 0; jj < 64; ++jj) {
            const int j = j0 + jj;
            float s0 = 0.f, s1 = 0.f, s2 = 0.f, s3 = 0.f;
            #pragma unroll
            for (int dq = 0; dq < 16; ++dq) {
                float4 k4 = *(const float4*)&Kbuf[jj * 64 + dq * 4];
                s0 = fmaf(q4[dq].x, k4.x, s0);
                s1 = fmaf(q4[dq].y, k4.y, s1);
                s2 = fmaf(q4[dq].z, k4.z, s2);
                s3 = fmaf(q4[dq].w, k4.w, s3);
            }
            float s = ((s0 + s1) + (s2 + s3)) * scale;
            bool valid = (j >= 0) && (j < SEQ) && (j >= i - WIN) && (j <= i + WIN);
            s = valid ? s : -1e30f;
            float p = __expf(s);
            l += p;
            #pragma unroll
            for (int dq = 0; dq < 16; ++dq) {
                float4 v4 = *(const float4*)&Vbuf[jj * 64 + dq * 4];
                acc4[dq].x = fmaf(p, v4.x, acc4[dq].x);
                acc4[dq].y = fmaf(p, v4.y, acc4[dq].y);
                acc4[dq].z = fmaf(p, v4.z, acc4[dq].z);
                acc4[dq].w = fmaf(p, v4.w, acc4[dq].w);
            }
        }
    }

    __syncthreads();
    float* abuf = smem + 4096;
    float* lbuf = smem;
    if (wv == 1) {
        #pragma unroll
        for (int dq = 0; dq < 16; ++dq)
            *(float4*)&abuf[lane * 65 + dq * 4] = acc4[dq];
        lbuf[lane] = l;
    }
    __syncthreads();
    if (wv == 0) {
        l += lbuf[lane];
        const float rl = 1.0f / l;
        unsigned short* obase = o + (size_t)i * D + h * HD;
        #pragma unroll
        for (int dq = 0; dq < 16; ++dq) {
            float4 a2 = *(const float4*)&abuf[lane * 65 + dq * 4];
            ushort4 u = make_ushort4(f2bf((acc4[dq].x + a2.x) * rl),
                                     f2bf((acc4[dq].y + a2.y) * rl),
                                     f2bf((acc4[dq].z + a2.z) * rl),
                                     f2bf((acc4[dq].w + a2.w) * rl));
            *(ushort4*)(obase + dq * 4) = u;
        }
    }
}

// ---------------------------------------------------------------------------
// out = LayerNorm(a + b) * g + beta; optionally also bf16 copy of out.
// One wave per 512-elem row.
// ---------------------------------------------------------------------------
template <bool DUAL>
__global__ __launch_bounds__(256) void add_ln(
    const float* __restrict__ a, const float* __restrict__ b,
    const float* __restrict__ g, const float* __restrict__ beta,
    float* __restrict__ out, unsigned short* __restrict__ outb)
{
    const int wave = threadIdx.x >> 6;
    const int lane = threadIdx.x & 63;
    const int row = blockIdx.x * 4 + wave;

    const float* pa = a + (size_t)row * D;
    const float* pb = b + (size_t)row * D;

    float v[8];
    float sum = 0.0f, sumsq = 0.0f;
    #pragma unroll
    for (int e = 0; e < 8; ++e) {
        float z = pa[lane + e * 64] + pb[lane + e * 64];
        v[e] = z;
        sum += z;
        sumsq += z * z;
    }
    #pragma unroll
    for (int off = 32; off; off >>= 1) {
        sum   += __shfl_xor(sum, off, 64);
        sumsq += __shfl_xor(sumsq, off, 64);
    }
    const float mu   = sum * (1.0f / D);
    const float var  = sumsq * (1.0f / D) - mu * mu;
    const float rstd = rsqrtf(var + LN_EPS);

    float* po = out + (size_t)row * D;
    #pragma unroll
    for (int e = 0; e < 8; ++e) {
        int c = lane + e * 64;
        float r = (v[e] - mu) * rstd * g[c] + beta[c];
        po[c] = r;
        if (DUAL) outb[(size_t)row * D + c] = f2bf(r);
    }
}

// ---------------------------------------------------------------------------
extern "C" void kernel_launch(void* const* d_in, const int* in_sizes, int n_in,
                              void* d_out, int out_size, void* d_ws, size_t ws_size,
                              hipStream_t stream)
{
    const float* x      = (const float*)d_in[0];
    const float* qkv_w  = (const float*)d_in[1];
    const float* qkv_b  = (const float*)d_in[2];
    const float* out_w  = (const float*)d_in[3];
    const float* out_b  = (const float*)d_in[4];
    const float* ln1_g  = (const float*)d_in[5];
    const float* ln1_b  = (const float*)d_in[6];
    const float* w1     = (const float*)d_in[7];
    const float* b1     = (const float*)d_in[8];
    const float* w2     = (const float*)d_in[9];
    const float* b2     = (const float*)d_in[10];
    const float* ln2_g  = (const float*)d_in[11];
    const float* ln2_b  = (const float*)d_in[12];
    float* out = (float*)d_out;

    // ---- workspace layout ----
    char* ws = (char*)d_ws;
    auto alloc = [&](size_t bytes) { char* p = ws; ws += (bytes + 255) & ~255ull; return p; };
    unsigned short* xb     = (unsigned short*)alloc((size_t)SEQ * D * 2);
    unsigned short* qkvw_t = (unsigned short*)alloc((size_t)3 * D * D * 2);   // [1536][512]
    unsigned short* outw_t = (unsigned short*)alloc((size_t)D * D * 2);       // [512][512]
    unsigned short* w1_t   = (unsigned short*)alloc((size_t)DFF * D * 2);     // [2048][512]
    unsigned short* w2_t   = (unsigned short*)alloc((size_t)D * DFF * 2);     // [512][2048]
    float*          qkv    = (float*)alloc((size_t)SEQ * 3 * D * 4);
    unsigned short* o_b    = (unsigned short*)alloc((size_t)SEQ * D * 2);
    float*          attn_o = (float*)alloc((size_t)SEQ * D * 4);
    float*          x1     = (float*)alloc((size_t)SEQ * D * 4);
    unsigned short* x1b    = (unsigned short*)alloc((size_t)SEQ * D * 2);
    unsigned short* ff1b   = (unsigned short*)alloc((size_t)SEQ * DFF * 2);
    float*          ff2    = (float*)alloc((size_t)SEQ * D * 4);

    // ---- conversions ----
    f32_to_bf16<<<(SEQ * D) / 1024, 256, 0, stream>>>(x, xb, SEQ * D);
    transpose_bf16<<<dim3(3 * D / 32, D / 32), dim3(32, 8), 0, stream>>>(qkv_w, qkvw_t, D, 3 * D);
    transpose_bf16<<<dim3(D / 32, D / 32),     dim3(32, 8), 0, stream>>>(out_w, outw_t, D, D);
    transpose_bf16<<<dim3(DFF / 32, D / 32),   dim3(32, 8), 0, stream>>>(w1, w1_t, D, DFF);
    transpose_bf16<<<dim3(D / 32, DFF / 32),   dim3(32, 8), 0, stream>>>(w2, w2_t, DFF, D);

    // 1) qkv = xb @ qkv_w + qkv_b  -> fp32 [4096,1536]
    gemm_mfma<false, false><<<dim3(3 * D / 128, SEQ / 128), 256, 0, stream>>>(
        xb, qkvw_t, qkv_b, qkv, SEQ, 3 * D, D);

    // 2) windowed attention -> o bf16 [4096,512]
    attn_flash<<<dim3(SEQ / 64, NH), 128, 0, stream>>>(qkv, o_b);

    // 3) attn_o = o @ out_w + out_b -> fp32
    gemm_mfma<false, false><<<dim3(D / 128, SEQ / 128), 256, 0, stream>>>(
        o_b, outw_t, out_b, attn_o, SEQ, D, D);

    // 4) x1 = LN(x + attn_o) -> fp32 + bf16
    add_ln<true><<<SEQ / 4, 256, 0, stream>>>(x, attn_o, ln1_g, ln1_b, x1, x1b);

    // 5) ff1 = relu(x1b @ w1 + b1) -> bf16 [4096,2048]
    gemm_mfma<true, true><<<dim3(DFF / 128, SEQ / 128), 256, 0, stream>>>(
        x1b, w1_t, b1, ff1b, SEQ, DFF, D);

    // 6) ff2 = ff1 @ w2 + b2 -> fp32 [4096,512]
    gemm_mfma<false, false><<<dim3(D / 128, SEQ / 128), 256, 0, stream>>>(
        ff1b, w2_t, b2, ff2, SEQ, D, DFF);

    // 7) out = LN(x1 + ff2)
    add_ln<false><<<SEQ / 4, 256, 0, stream>>>(x1, ff2, ln2_g, ln2_b, out, nullptr);
}

// Round 4
// 146.947 us; speedup vs baseline: 7.5542x; 2.4672x over previous
//
#include <hip/hip_runtime.h>
#include <math.h>

// Problem constants
constexpr int D      = 512;
constexpr int NH     = 8;
constexpr int HD     = 64;
constexpr int WIN    = 128;
constexpr int DFF    = 2048;
constexpr int SEQ    = 4096;
constexpr float LN_EPS = 1e-5f;

typedef float f32x4 __attribute__((ext_vector_type(4)));
typedef __bf16 bf16x8 __attribute__((ext_vector_type(8)));

__device__ __forceinline__ unsigned short f2bf(float f) {
    union { float f; unsigned u; } v; v.f = f;
    unsigned r = v.u + 0x7FFF + ((v.u >> 16) & 1);   // round-to-nearest-even
    return (unsigned short)(r >> 16);
}

__device__ __forceinline__ void gload16(const void* g, void* l) {
    __builtin_amdgcn_global_load_lds(
        (const __attribute__((address_space(1))) unsigned int*)g,
        (__attribute__((address_space(3))) unsigned int*)l,
        16, 0, 0);
}

// ---------------------------------------------------------------------------
// fp32 -> bf16 elementwise (4 elems/thread)
// ---------------------------------------------------------------------------
__global__ __launch_bounds__(256) void f32_to_bf16(
    const float* __restrict__ in, unsigned short* __restrict__ out, int n)
{
    int i = (blockIdx.x * 256 + threadIdx.x) * 4;
    if (i >= n) return;
    float4 v = *(const float4*)(in + i);
    ushort4 u = make_ushort4(f2bf(v.x), f2bf(v.y), f2bf(v.z), f2bf(v.w));
    *(ushort4*)(out + i) = u;
}

// ---------------------------------------------------------------------------
// W [K][N] fp32 -> Wt [N][K] bf16 (32x32 LDS tile transpose)
// ---------------------------------------------------------------------------
__global__ __launch_bounds__(256) void transpose_bf16(
    const float* __restrict__ W, unsigned short* __restrict__ Wt, int K, int N)
{
    __shared__ float t[32][33];
    const int n0 = blockIdx.x * 32, k0 = blockIdx.y * 32;
    #pragma unroll
    for (int r = 0; r < 4; ++r)
        t[threadIdx.y + r * 8][threadIdx.x] =
            W[(size_t)(k0 + threadIdx.y + r * 8) * N + n0 + threadIdx.x];
    __syncthreads();
    #pragma unroll
    for (int r = 0; r < 4; ++r)
        Wt[(size_t)(n0 + threadIdx.y + r * 8) * K + k0 + threadIdx.x] =
            f2bf(t[threadIdx.x][threadIdx.y + r * 8]);
}

// ---------------------------------------------------------------------------
// MFMA GEMM: C[M,N] = A[M,K](bf16) @ Bt[N,K](bf16)^T + bias, opt ReLU,
// output fp32 or bf16. 128x128 tile, BK=32, 4 waves each 64x64.
// ---------------------------------------------------------------------------
template <bool RELU, bool OUT_BF16>
__global__ __launch_bounds__(256) void gemm_mfma(
    const unsigned short* __restrict__ A,
    const unsigned short* __restrict__ Bt,
    const float* __restrict__ bias,
    void* __restrict__ Cv, int M, int N, int K)
{
    __shared__ __align__(16) char lds[16384];

    const int tid  = threadIdx.x;
    const int lane = tid & 63;
    const int wave = tid >> 6;
    const int wr = wave >> 1, wc = wave & 1;
    const int m0 = blockIdx.y * 128, n0 = blockIdx.x * 128;

    f32x4 acc[4][4];
    #pragma unroll
    for (int m = 0; m < 4; ++m)
        #pragma unroll
        for (int n = 0; n < 4; ++n)
            acc[m][n] = f32x4{0.f, 0.f, 0.f, 0.f};

    const int lr = lane & 15, lk = lane >> 4;
    const int aoff = ((wr * 64 + lr) << 6) + (lk << 4);
    const int boff = 8192 + ((wc * 64 + lr) << 6) + (lk << 4);

    const int srow = (tid * 16) >> 6;
    const int skb  = (tid * 16) & 63;

    for (int k0 = 0; k0 < K; k0 += 32) {
        #pragma unroll
        for (int r = 0; r < 2; ++r) {
            int row = srow + r * 64;
            gload16((const char*)A + ((size_t)(m0 + row) * K + k0) * 2 + skb,
                    lds + r * 4096 + tid * 16);
        }
        #pragma unroll
        for (int r = 0; r < 2; ++r) {
            int row = srow + r * 64;
            gload16((const char*)Bt + ((size_t)(n0 + row) * K + k0) * 2 + skb,
                    lds + 8192 + r * 4096 + tid * 16);
        }
        __syncthreads();

        bf16x8 af[4], bfv[4];
        #pragma unroll
        for (int m = 0; m < 4; ++m)
            af[m] = *(const bf16x8*)(lds + aoff + m * 1024);
        #pragma unroll
        for (int n = 0; n < 4; ++n)
            bfv[n] = *(const bf16x8*)(lds + boff + n * 1024);

        #pragma unroll
        for (int m = 0; m < 4; ++m)
            #pragma unroll
            for (int n = 0; n < 4; ++n)
                acc[m][n] = __builtin_amdgcn_mfma_f32_16x16x32_bf16(
                    af[m], bfv[n], acc[m][n], 0, 0, 0);
        __syncthreads();
    }

    const int col0 = n0 + wc * 64 + lr;
    const int row0 = m0 + wr * 64 + lk * 4;
    #pragma unroll
    for (int m = 0; m < 4; ++m) {
        #pragma unroll
        for (int n = 0; n < 4; ++n) {
            int col = col0 + n * 16;
            float bv = bias[col];
            #pragma unroll
            for (int j = 0; j < 4; ++j) {
                int row = row0 + m * 16 + j;
                float v = acc[m][n][j] + bv;
                if (RELU) v = fmaxf(v, 0.0f);
                if (OUT_BF16)
                    ((unsigned short*)Cv)[(size_t)row * N + col] = f2bf(v);
                else
                    ((float*)Cv)[(size_t)row * N + col] = v;
            }
        }
    }
}

// ---------------------------------------------------------------------------
// QKV GEMM: same main loop; epilogue scatters to attention-friendly layouts:
//   qb[h][row][d], kb[h][row][d]  (bf16, [NH][SEQ][64])
//   vtb[h][d][row]                (bf16, [NH][64][SEQ], transposed)
// N = 1536, K = 512 fixed; block cols never cross a Q/K/V boundary.
// ---------------------------------------------------------------------------
__global__ __launch_bounds__(256) void gemm_qkv(
    const unsigned short* __restrict__ A,
    const unsigned short* __restrict__ Bt,
    const float* __restrict__ bias,
    unsigned short* __restrict__ qb,
    unsigned short* __restrict__ kb,
    unsigned short* __restrict__ vtb)
{
    constexpr int N = 3 * D, K = D;
    __shared__ __align__(16) char lds[16384];

    const int tid  = threadIdx.x;
    const int lane = tid & 63;
    const int wave = tid >> 6;
    const int wr = wave >> 1, wc = wave & 1;
    const int m0 = blockIdx.y * 128, n0 = blockIdx.x * 128;

    f32x4 acc[4][4];
    #pragma unroll
    for (int m = 0; m < 4; ++m)
        #pragma unroll
        for (int n = 0; n < 4; ++n)
            acc[m][n] = f32x4{0.f, 0.f, 0.f, 0.f};

    const int lr = lane & 15, lk = lane >> 4;
    const int aoff = ((wr * 64 + lr) << 6) + (lk << 4);
    const int boff = 8192 + ((wc * 64 + lr) << 6) + (lk << 4);
    const int srow = (tid * 16) >> 6;
    const int skb  = (tid * 16) & 63;

    for (int k0 = 0; k0 < K; k0 += 32) {
        #pragma unroll
        for (int r = 0; r < 2; ++r) {
            int row = srow + r * 64;
            gload16((const char*)A + ((size_t)(m0 + row) * K + k0) * 2 + skb,
                    lds + r * 4096 + tid * 16);
        }
        #pragma unroll
        for (int r = 0; r < 2; ++r) {
            int row = srow + r * 64;
            gload16((const char*)Bt + ((size_t)(n0 + row) * K + k0) * 2 + skb,
                    lds + 8192 + r * 4096 + tid * 16);
        }
        __syncthreads();

        bf16x8 af[4], bfv[4];
        #pragma unroll
        for (int m = 0; m < 4; ++m)
            af[m] = *(const bf16x8*)(lds + aoff + m * 1024);
        #pragma unroll
        for (int n = 0; n < 4; ++n)
            bfv[n] = *(const bf16x8*)(lds + boff + n * 1024);

        #pragma unroll
        for (int m = 0; m < 4; ++m)
            #pragma unroll
            for (int n = 0; n < 4; ++n)
                acc[m][n] = __builtin_amdgcn_mfma_f32_16x16x32_bf16(
                    af[m], bfv[n], acc[m][n], 0, 0, 0);
        __syncthreads();
    }

    const int col0 = n0 + wc * 64 + lr;
    const int row0 = m0 + wr * 64 + lk * 4;
    const int region = n0 >> 9;   // 0=Q, 1=K, 2=V (uniform per block)
    #pragma unroll
    for (int m = 0; m < 4; ++m) {
        #pragma unroll
        for (int n = 0; n < 4; ++n) {
            const int col = col0 + n * 16;
            const float bv = bias[col];
            const int rowm = row0 + m * 16;
            if (region == 2) {
                const int cc = col - 1024, hh = cc >> 6, dd = cc & 63;
                ushort4 u = make_ushort4(f2bf(acc[m][n][0] + bv),
                                         f2bf(acc[m][n][1] + bv),
                                         f2bf(acc[m][n][2] + bv),
                                         f2bf(acc[m][n][3] + bv));
                *(ushort4*)&vtb[((size_t)(hh * 64 + dd)) * SEQ + rowm] = u;
            } else {
                const int cc = col - region * 512, hh = cc >> 6, dd = cc & 63;
                unsigned short* dst = (region == 0) ? qb : kb;
                #pragma unroll
                for (int j = 0; j < 4; ++j)
                    dst[((size_t)hh * SEQ + rowm + j) * 64 + dd] =
                        f2bf(acc[m][n][j] + bv);
            }
        }
    }
}

// ---------------------------------------------------------------------------
// MFMA windowed attention. Block = 256 thr (4 waves) per (64-query tile, head).
// Wave w owns queries [i0+w*16, i0+w*16+16). Per 64-key chunk:
//   S^T = mfma(K,Q)  (cols=q, rows=k)  -> p=exp2(s*SC) masked ->
//   pack 4 consecutive-k bf16 -> wave-private P_lds[16q][64k] (A-layout) ->
//   O += mfma(P, Vt). Softmax is a pure sum (scores O(1)): no max, no
//   rescale; normalize once at the end. No barriers; K/V/Q fragments loaded
//   directly from global (L2-resident bf16 buffers written by gemm_qkv).
// ---------------------------------------------------------------------------
__global__ __launch_bounds__(256) void attn_mfma(
    const unsigned short* __restrict__ qb,   // [NH][SEQ][64]
    const unsigned short* __restrict__ kb,   // [NH][SEQ][64]
    const unsigned short* __restrict__ vtb,  // [NH][64][SEQ]
    unsigned short* __restrict__ o)          // [SEQ][512] bf16
{
    constexpr float SCALE_L2E = 0.044194173824159216f * 1.4426950408889634f;
    __shared__ __align__(16) unsigned short P_lds[4][16][72];  // pitch 72: 2-way banks

    const int tid  = threadIdx.x;
    const int lane = tid & 63;
    const int w    = tid >> 6;
    const int i0   = blockIdx.x * 64;
    const int h    = blockIdx.y;
    const int lr = lane & 15, lg = lane >> 4;

    const unsigned short* qh = qb  + (size_t)h * SEQ * 64;
    const unsigned short* kh = kb  + (size_t)h * SEQ * 64;
    const unsigned short* vh = vtb + (size_t)h * 64 * SEQ;

    // Q fragments (Y-operand): row q = i0+w*16+lr, elems d = s*32 + lg*8
    bf16x8 bq[2];
    {
        const unsigned short* qrow = qh + (size_t)(i0 + w * 16 + lr) * 64 + lg * 8;
        bq[0] = *(const bf16x8*)qrow;
        bq[1] = *(const bf16x8*)(qrow + 32);
    }

    f32x4 accO[4];
    #pragma unroll
    for (int n = 0; n < 4; ++n) accO[n] = f32x4{0.f, 0.f, 0.f, 0.f};
    float lsum = 0.0f;
    const int iq = i0 + w * 16 + lr;   // this lane's query (S^T col)

    for (int c = 0; c < 5; ++c) {
        const int j0 = i0 - WIN + c * 64;
        if (j0 < 0 || j0 >= SEQ) continue;   // valid chunks always fully in-range

        // K fragments (X): row k = j0 + m*16 + lr, elems d = s*32 + lg*8
        bf16x8 ak[2][4];
        #pragma unroll
        for (int m = 0; m < 4; ++m) {
            const unsigned short* kr = kh + (size_t)(j0 + m * 16 + lr) * 64 + lg * 8;
            ak[0][m] = *(const bf16x8*)kr;
            ak[1][m] = *(const bf16x8*)(kr + 32);
        }
        // V^T fragments (Y): row d = n*16 + lr, elems j = j0 + s*32 + lg*8
        bf16x8 bv[2][4];
        #pragma unroll
        for (int n = 0; n < 4; ++n) {
            const unsigned short* vr = vh + (size_t)(n * 16 + lr) * SEQ + j0 + lg * 8;
            bv[0][n] = *(const bf16x8*)vr;
            bv[1][n] = *(const bf16x8*)(vr + 32);
        }

        // S^T = K·Q^T : frag m rows k = j0+m*16+lg*4+j, col q = iq
        f32x4 accS[4];
        #pragma unroll
        for (int m = 0; m < 4; ++m) {
            accS[m] = f32x4{0.f, 0.f, 0.f, 0.f};
            #pragma unroll
            for (int s = 0; s < 2; ++s)
                accS[m] = __builtin_amdgcn_mfma_f32_16x16x32_bf16(
                    ak[s][m], bq[s], accS[m], 0, 0, 0);
        }

        // p = exp(s*scale) masked; pack 4 consecutive k -> P_lds[q][k]
        #pragma unroll
        for (int m = 0; m < 4; ++m) {
            const int kbase = j0 + m * 16 + lg * 4;
            float p0, p1, p2, p3;
            {
                int d0 = kbase + 0 - iq; bool v0 = (d0 >= -WIN) && (d0 <= WIN);
                int d1 = kbase + 1 - iq; bool v1 = (d1 >= -WIN) && (d1 <= WIN);
                int d2 = kbase + 2 - iq; bool v2 = (d2 >= -WIN) && (d2 <= WIN);
                int d3 = kbase + 3 - iq; bool v3 = (d3 >= -WIN) && (d3 <= WIN);
                p0 = v0 ? exp2f(accS[m][0] * SCALE_L2E) : 0.0f;
                p1 = v1 ? exp2f(accS[m][1] * SCALE_L2E) : 0.0f;
                p2 = v2 ? exp2f(accS[m][2] * SCALE_L2E) : 0.0f;
                p3 = v3 ? exp2f(accS[m][3] * SCALE_L2E) : 0.0f;
            }
            lsum += (p0 + p1) + (p2 + p3);
            ushort4 pk = make_ushort4(f2bf(p0), f2bf(p1), f2bf(p2), f2bf(p3));
            *(ushort4*)&P_lds[w][lr][m * 16 + lg * 4] = pk;
        }

        // P fragments (X): row q = lr, elems k = s*32 + lg*8 (same wave: no barrier)
        bf16x8 pa[2];
        pa[0] = *(const bf16x8*)&P_lds[w][lr][lg * 8];
        pa[1] = *(const bf16x8*)&P_lds[w][lr][32 + lg * 8];

        #pragma unroll
        for (int n = 0; n < 4; ++n)
            #pragma unroll
            for (int s = 0; s < 2; ++s)
                accO[n] = __builtin_amdgcn_mfma_f32_16x16x32_bf16(
                    pa[s], bv[s][n], accO[n], 0, 0, 0);
    }

    // l[q] finish: reduce across lane-groups (same lr), then redistribute to
    // O's C-layout rows (q = lg*4 + j).
    lsum += __shfl_xor(lsum, 16, 64);
    lsum += __shfl_xor(lsum, 32, 64);
    float rinv[4];
    #pragma unroll
    for (int j = 0; j < 4; ++j)
        rinv[j] = 1.0f / __shfl(lsum, lg * 4 + j, 64);

    #pragma unroll
    for (int n = 0; n < 4; ++n)
        #pragma unroll
        for (int j = 0; j < 4; ++j) {
            int row = i0 + w * 16 + lg * 4 + j;
            int col = h * 64 + n * 16 + lr;
            o[(size_t)row * D + col] = f2bf(accO[n][j] * rinv[j]);
        }
}

// ---------------------------------------------------------------------------
// out = LayerNorm(a + b) * g + beta; optionally also bf16 copy.
// ---------------------------------------------------------------------------
template <bool DUAL>
__global__ __launch_bounds__(256) void add_ln(
    const float* __restrict__ a, const float* __restrict__ b,
    const float* __restrict__ g, const float* __restrict__ beta,
    float* __restrict__ out, unsigned short* __restrict__ outb)
{
    const int wave = threadIdx.x >> 6;
    const int lane = threadIdx.x & 63;
    const int row = blockIdx.x * 4 + wave;

    const float* pa = a + (size_t)row * D;
    const float* pb = b + (size_t)row * D;

    float v[8];
    float sum = 0.0f, sumsq = 0.0f;
    #pragma unroll
    for (int e = 0; e < 8; ++e) {
        float z = pa[lane + e * 64] + pb[lane + e * 64];
        v[e] = z;
        sum += z;
        sumsq += z * z;
    }
    #pragma unroll
    for (int off = 32; off; off >>= 1) {
        sum   += __shfl_xor(sum, off, 64);
        sumsq += __shfl_xor(sumsq, off, 64);
    }
    const float mu   = sum * (1.0f / D);
    const float var  = sumsq * (1.0f / D) - mu * mu;
    const float rstd = rsqrtf(var + LN_EPS);

    float* po = out + (size_t)row * D;
    #pragma unroll
    for (int e = 0; e < 8; ++e) {
        int c = lane + e * 64;
        float r = (v[e] - mu) * rstd * g[c] + beta[c];
        po[c] = r;
        if (DUAL) outb[(size_t)row * D + c] = f2bf(r);
    }
}

// ---------------------------------------------------------------------------
extern "C" void kernel_launch(void* const* d_in, const int* in_sizes, int n_in,
                              void* d_out, int out_size, void* d_ws, size_t ws_size,
                              hipStream_t stream)
{
    const float* x      = (const float*)d_in[0];
    const float* qkv_w  = (const float*)d_in[1];
    const float* qkv_b  = (const float*)d_in[2];
    const float* out_w  = (const float*)d_in[3];
    const float* out_b  = (const float*)d_in[4];
    const float* ln1_g  = (const float*)d_in[5];
    const float* ln1_b  = (const float*)d_in[6];
    const float* w1     = (const float*)d_in[7];
    const float* b1     = (const float*)d_in[8];
    const float* w2     = (const float*)d_in[9];
    const float* b2     = (const float*)d_in[10];
    const float* ln2_g  = (const float*)d_in[11];
    const float* ln2_b  = (const float*)d_in[12];
    float* out = (float*)d_out;

    // ---- workspace layout ----
    char* ws = (char*)d_ws;
    auto alloc = [&](size_t bytes) { char* p = ws; ws += (bytes + 255) & ~255ull; return p; };
    unsigned short* xb     = (unsigned short*)alloc((size_t)SEQ * D * 2);
    unsigned short* qkvw_t = (unsigned short*)alloc((size_t)3 * D * D * 2);
    unsigned short* outw_t = (unsigned short*)alloc((size_t)D * D * 2);
    unsigned short* w1_t   = (unsigned short*)alloc((size_t)DFF * D * 2);
    unsigned short* w2_t   = (unsigned short*)alloc((size_t)D * DFF * 2);
    unsigned short* qbuf   = (unsigned short*)alloc((size_t)NH * SEQ * 64 * 2);
    unsigned short* kbuf   = (unsigned short*)alloc((size_t)NH * SEQ * 64 * 2);
    unsigned short* vtbuf  = (unsigned short*)alloc((size_t)NH * 64 * SEQ * 2);
    unsigned short* o_b    = (unsigned short*)alloc((size_t)SEQ * D * 2);
    float*          attn_o = (float*)alloc((size_t)SEQ * D * 4);
    float*          x1     = (float*)alloc((size_t)SEQ * D * 4);
    unsigned short* x1b    = (unsigned short*)alloc((size_t)SEQ * D * 2);
    unsigned short* ff1b   = (unsigned short*)alloc((size_t)SEQ * DFF * 2);
    float*          ff2    = (float*)alloc((size_t)SEQ * D * 4);

    // ---- conversions ----
    f32_to_bf16<<<(SEQ * D) / 1024, 256, 0, stream>>>(x, xb, SEQ * D);
    transpose_bf16<<<dim3(3 * D / 32, D / 32), dim3(32, 8), 0, stream>>>(qkv_w, qkvw_t, D, 3 * D);
    transpose_bf16<<<dim3(D / 32, D / 32),     dim3(32, 8), 0, stream>>>(out_w, outw_t, D, D);
    transpose_bf16<<<dim3(DFF / 32, D / 32),   dim3(32, 8), 0, stream>>>(w1, w1_t, D, DFF);
    transpose_bf16<<<dim3(D / 32, DFF / 32),   dim3(32, 8), 0, stream>>>(w2, w2_t, DFF, D);

    // 1) qkv projection -> qb/kb/vtb (attention layouts)
    gemm_qkv<<<dim3(3 * D / 128, SEQ / 128), 256, 0, stream>>>(
        xb, qkvw_t, qkv_b, qbuf, kbuf, vtbuf);

    // 2) MFMA windowed attention -> o bf16 [4096,512]
    attn_mfma<<<dim3(SEQ / 64, NH), 256, 0, stream>>>(qbuf, kbuf, vtbuf, o_b);

    // 3) attn_o = o @ out_w + out_b -> fp32
    gemm_mfma<false, false><<<dim3(D / 128, SEQ / 128), 256, 0, stream>>>(
        o_b, outw_t, out_b, attn_o, SEQ, D, D);

    // 4) x1 = LN(x + attn_o) -> fp32 + bf16
    add_ln<true><<<SEQ / 4, 256, 0, stream>>>(x, attn_o, ln1_g, ln1_b, x1, x1b);

    // 5) ff1 = relu(x1b @ w1 + b1) -> bf16 [4096,2048]
    gemm_mfma<true, true><<<dim3(DFF / 128, SEQ / 128), 256, 0, stream>>>(
        x1b, w1_t, b1, ff1b, SEQ, DFF, D);

    // 6) ff2 = ff1 @ w2 + b2 -> fp32 [4096,512]
    gemm_mfma<false, false><<<dim3(D / 128, SEQ / 128), 256, 0, stream>>>(
        ff1b, w2_t, b2, ff2, SEQ, D, DFF);

    // 7) out = LN(x1 + ff2)
    add_ln<false><<<SEQ / 4, 256, 0, stream>>>(x1, ff2, ln2_g, ln2_b, out, nullptr);
}

// Round 5
// 121.284 us; speedup vs baseline: 9.1526x; 1.2116x over previous
//
#include <hip/hip_runtime.h>
#include <math.h>

// Problem constants
constexpr int D      = 512;
constexpr int NH     = 8;
constexpr int HD     = 64;
constexpr int WIN    = 128;
constexpr int DFF    = 2048;
constexpr int SEQ    = 4096;
constexpr float LN_EPS = 1e-5f;

typedef float f32x4 __attribute__((ext_vector_type(4)));
typedef __bf16 bf16x8 __attribute__((ext_vector_type(8)));

__device__ __forceinline__ unsigned short f2bf(float f) {
    union { float f; unsigned u; } v; v.f = f;
    unsigned r = v.u + 0x7FFF + ((v.u >> 16) & 1);   // round-to-nearest-even
    return (unsigned short)(r >> 16);
}

__device__ __forceinline__ void gload16(const void* g, void* l) {
    __builtin_amdgcn_global_load_lds(
        (const __attribute__((address_space(1))) unsigned int*)g,
        (__attribute__((address_space(3))) unsigned int*)l,
        16, 0, 0);
}

// ---------------------------------------------------------------------------
// fp32 -> bf16 elementwise (4 elems/thread)
// ---------------------------------------------------------------------------
__global__ __launch_bounds__(256) void f32_to_bf16(
    const float* __restrict__ in, unsigned short* __restrict__ out, int n)
{
    int i = (blockIdx.x * 256 + threadIdx.x) * 4;
    if (i >= n) return;
    float4 v = *(const float4*)(in + i);
    ushort4 u = make_ushort4(f2bf(v.x), f2bf(v.y), f2bf(v.z), f2bf(v.w));
    *(ushort4*)(out + i) = u;
}

// ---------------------------------------------------------------------------
// All 4 weight transposes in one kernel. W [K][N] fp32 -> Wt [N][K] bf16.
// 32x32 tiles, block (32,8). Segments by linear blockIdx.x:
//   [0,768)    qkv_w  K=512  N=1536
//   [768,1024) out_w  K=512  N=512
//   [1024,2048) w1    K=512  N=2048
//   [2048,3072) w2    K=2048 N=512
// ---------------------------------------------------------------------------
__global__ __launch_bounds__(256) void transpose_all(
    const float* __restrict__ qkv_w, const float* __restrict__ out_w,
    const float* __restrict__ w1,    const float* __restrict__ w2,
    unsigned short* __restrict__ qkvw_t, unsigned short* __restrict__ outw_t,
    unsigned short* __restrict__ w1_t,   unsigned short* __restrict__ w2_t)
{
    __shared__ float t[32][33];
    int b = blockIdx.x;
    const float* W; unsigned short* Wt; int K, N, nt, kt;
    if (b < 768)       { W = qkv_w; Wt = qkvw_t; K = 512;  N = 1536; nt = b % 48;            kt = b / 48; }
    else if (b < 1024) { W = out_w; Wt = outw_t; K = 512;  N = 512;  nt = (b - 768) % 16;    kt = (b - 768) / 16; }
    else if (b < 2048) { W = w1;    Wt = w1_t;   K = 512;  N = 2048; nt = (b - 1024) % 64;   kt = (b - 1024) / 64; }
    else               { W = w2;    Wt = w2_t;   K = 2048; N = 512;  nt = (b - 2048) % 16;   kt = (b - 2048) / 16; }
    const int n0 = nt * 32, k0 = kt * 32;
    #pragma unroll
    for (int r = 0; r < 4; ++r)
        t[threadIdx.y + r * 8][threadIdx.x] =
            W[(size_t)(k0 + threadIdx.y + r * 8) * N + n0 + threadIdx.x];
    __syncthreads();
    #pragma unroll
    for (int r = 0; r < 4; ++r)
        Wt[(size_t)(n0 + threadIdx.y + r * 8) * K + k0 + threadIdx.x] =
            f2bf(t[threadIdx.x][threadIdx.y + r * 8]);
}

// ---------------------------------------------------------------------------
// MFMA GEMM (monolithic): C = A @ Bt^T + bias, opt ReLU, bf16 out (FF1 use).
// 128x128 tile, BK=32, 4 waves each 64x64.
// ---------------------------------------------------------------------------
template <bool RELU, bool OUT_BF16>
__global__ __launch_bounds__(256) void gemm_mfma(
    const unsigned short* __restrict__ A,
    const unsigned short* __restrict__ Bt,
    const float* __restrict__ bias,
    void* __restrict__ Cv, int M, int N, int K)
{
    __shared__ __align__(16) char lds[16384];

    const int tid  = threadIdx.x;
    const int lane = tid & 63;
    const int wave = tid >> 6;
    const int wr = wave >> 1, wc = wave & 1;
    const int m0 = blockIdx.y * 128, n0 = blockIdx.x * 128;

    f32x4 acc[4][4];
    #pragma unroll
    for (int m = 0; m < 4; ++m)
        #pragma unroll
        for (int n = 0; n < 4; ++n)
            acc[m][n] = f32x4{0.f, 0.f, 0.f, 0.f};

    const int lr = lane & 15, lk = lane >> 4;
    const int aoff = ((wr * 64 + lr) << 6) + (lk << 4);
    const int boff = 8192 + ((wc * 64 + lr) << 6) + (lk << 4);
    const int srow = (tid * 16) >> 6;
    const int skb  = (tid * 16) & 63;

    for (int k0 = 0; k0 < K; k0 += 32) {
        #pragma unroll
        for (int r = 0; r < 2; ++r) {
            int row = srow + r * 64;
            gload16((const char*)A + ((size_t)(m0 + row) * K + k0) * 2 + skb,
                    lds + r * 4096 + tid * 16);
        }
        #pragma unroll
        for (int r = 0; r < 2; ++r) {
            int row = srow + r * 64;
            gload16((const char*)Bt + ((size_t)(n0 + row) * K + k0) * 2 + skb,
                    lds + 8192 + r * 4096 + tid * 16);
        }
        __syncthreads();

        bf16x8 af[4], bfv[4];
        #pragma unroll
        for (int m = 0; m < 4; ++m)
            af[m] = *(const bf16x8*)(lds + aoff + m * 1024);
        #pragma unroll
        for (int n = 0; n < 4; ++n)
            bfv[n] = *(const bf16x8*)(lds + boff + n * 1024);

        #pragma unroll
        for (int m = 0; m < 4; ++m)
            #pragma unroll
            for (int n = 0; n < 4; ++n)
                acc[m][n] = __builtin_amdgcn_mfma_f32_16x16x32_bf16(
                    af[m], bfv[n], acc[m][n], 0, 0, 0);
        __syncthreads();
    }

    const int col0 = n0 + wc * 64 + lr;
    const int row0 = m0 + wr * 64 + lk * 4;
    #pragma unroll
    for (int m = 0; m < 4; ++m) {
        #pragma unroll
        for (int n = 0; n < 4; ++n) {
            int col = col0 + n * 16;
            float bv = bias[col];
            #pragma unroll
            for (int j = 0; j < 4; ++j) {
                int row = row0 + m * 16 + j;
                float v = acc[m][n][j] + bv;
                if (RELU) v = fmaxf(v, 0.0f);
                if (OUT_BF16)
                    ((unsigned short*)Cv)[(size_t)row * N + col] = f2bf(v);
                else
                    ((float*)Cv)[(size_t)row * N + col] = v;
            }
        }
    }
}

// ---------------------------------------------------------------------------
// Split-K MFMA GEMM: chunk z covers K range [z*Kc, (z+1)*Kc); writes fp32
// partial to P + z*M*N. Bias added in chunk 0 only. Combine happens in the
// following add_ln_np kernel (deterministic fixed-order sum).
// ---------------------------------------------------------------------------
__global__ __launch_bounds__(256) void gemm_splitk(
    const unsigned short* __restrict__ A,
    const unsigned short* __restrict__ Bt,
    const float* __restrict__ bias,
    float* __restrict__ P, int M, int N, int K, int Kc)
{
    __shared__ __align__(16) char lds[16384];

    const int tid  = threadIdx.x;
    const int lane = tid & 63;
    const int wave = tid >> 6;
    const int wr = wave >> 1, wc = wave & 1;
    const int m0 = blockIdx.y * 128, n0 = blockIdx.x * 128;
    const int zc = blockIdx.z;
    const int kbeg = zc * Kc, kend = kbeg + Kc;

    f32x4 acc[4][4];
    #pragma unroll
    for (int m = 0; m < 4; ++m)
        #pragma unroll
        for (int n = 0; n < 4; ++n)
            acc[m][n] = f32x4{0.f, 0.f, 0.f, 0.f};

    const int lr = lane & 15, lk = lane >> 4;
    const int aoff = ((wr * 64 + lr) << 6) + (lk << 4);
    const int boff = 8192 + ((wc * 64 + lr) << 6) + (lk << 4);
    const int srow = (tid * 16) >> 6;
    const int skb  = (tid * 16) & 63;

    for (int k0 = kbeg; k0 < kend; k0 += 32) {
        #pragma unroll
        for (int r = 0; r < 2; ++r) {
            int row = srow + r * 64;
            gload16((const char*)A + ((size_t)(m0 + row) * K + k0) * 2 + skb,
                    lds + r * 4096 + tid * 16);
        }
        #pragma unroll
        for (int r = 0; r < 2; ++r) {
            int row = srow + r * 64;
            gload16((const char*)Bt + ((size_t)(n0 + row) * K + k0) * 2 + skb,
                    lds + 8192 + r * 4096 + tid * 16);
        }
        __syncthreads();

        bf16x8 af[4], bfv[4];
        #pragma unroll
        for (int m = 0; m < 4; ++m)
            af[m] = *(const bf16x8*)(lds + aoff + m * 1024);
        #pragma unroll
        for (int n = 0; n < 4; ++n)
            bfv[n] = *(const bf16x8*)(lds + boff + n * 1024);

        #pragma unroll
        for (int m = 0; m < 4; ++m)
            #pragma unroll
            for (int n = 0; n < 4; ++n)
                acc[m][n] = __builtin_amdgcn_mfma_f32_16x16x32_bf16(
                    af[m], bfv[n], acc[m][n], 0, 0, 0);
        __syncthreads();
    }

    float* Cp = P + (size_t)zc * M * N;
    const int col0 = n0 + wc * 64 + lr;
    const int row0 = m0 + wr * 64 + lk * 4;
    #pragma unroll
    for (int m = 0; m < 4; ++m) {
        #pragma unroll
        for (int n = 0; n < 4; ++n) {
            int col = col0 + n * 16;
            float bv = (zc == 0) ? bias[col] : 0.0f;
            #pragma unroll
            for (int j = 0; j < 4; ++j) {
                int row = row0 + m * 16 + j;
                Cp[(size_t)row * N + col] = acc[m][n][j] + bv;
            }
        }
    }
}

// ---------------------------------------------------------------------------
// QKV GEMM with attention-layout epilogue: qb/kb [NH][SEQ][64], vtb [NH][64][SEQ].
// ---------------------------------------------------------------------------
__global__ __launch_bounds__(256) void gemm_qkv(
    const unsigned short* __restrict__ A,
    const unsigned short* __restrict__ Bt,
    const float* __restrict__ bias,
    unsigned short* __restrict__ qb,
    unsigned short* __restrict__ kb,
    unsigned short* __restrict__ vtb)
{
    constexpr int N = 3 * D, K = D;
    __shared__ __align__(16) char lds[16384];

    const int tid  = threadIdx.x;
    const int lane = tid & 63;
    const int wave = tid >> 6;
    const int wr = wave >> 1, wc = wave & 1;
    const int m0 = blockIdx.y * 128, n0 = blockIdx.x * 128;

    f32x4 acc[4][4];
    #pragma unroll
    for (int m = 0; m < 4; ++m)
        #pragma unroll
        for (int n = 0; n < 4; ++n)
            acc[m][n] = f32x4{0.f, 0.f, 0.f, 0.f};

    const int lr = lane & 15, lk = lane >> 4;
    const int aoff = ((wr * 64 + lr) << 6) + (lk << 4);
    const int boff = 8192 + ((wc * 64 + lr) << 6) + (lk << 4);
    const int srow = (tid * 16) >> 6;
    const int skb  = (tid * 16) & 63;

    for (int k0 = 0; k0 < K; k0 += 32) {
        #pragma unroll
        for (int r = 0; r < 2; ++r) {
            int row = srow + r * 64;
            gload16((const char*)A + ((size_t)(m0 + row) * K + k0) * 2 + skb,
                    lds + r * 4096 + tid * 16);
        }
        #pragma unroll
        for (int r = 0; r < 2; ++r) {
            int row = srow + r * 64;
            gload16((const char*)Bt + ((size_t)(n0 + row) * K + k0) * 2 + skb,
                    lds + 8192 + r * 4096 + tid * 16);
        }
        __syncthreads();

        bf16x8 af[4], bfv[4];
        #pragma unroll
        for (int m = 0; m < 4; ++m)
            af[m] = *(const bf16x8*)(lds + aoff + m * 1024);
        #pragma unroll
        for (int n = 0; n < 4; ++n)
            bfv[n] = *(const bf16x8*)(lds + boff + n * 1024);

        #pragma unroll
        for (int m = 0; m < 4; ++m)
            #pragma unroll
            for (int n = 0; n < 4; ++n)
                acc[m][n] = __builtin_amdgcn_mfma_f32_16x16x32_bf16(
                    af[m], bfv[n], acc[m][n], 0, 0, 0);
        __syncthreads();
    }

    const int col0 = n0 + wc * 64 + lr;
    const int row0 = m0 + wr * 64 + lk * 4;
    const int region = n0 >> 9;   // 0=Q, 1=K, 2=V (uniform per block)
    #pragma unroll
    for (int m = 0; m < 4; ++m) {
        #pragma unroll
        for (int n = 0; n < 4; ++n) {
            const int col = col0 + n * 16;
            const float bv = bias[col];
            const int rowm = row0 + m * 16;
            if (region == 2) {
                const int cc = col - 1024, hh = cc >> 6, dd = cc & 63;
                ushort4 u = make_ushort4(f2bf(acc[m][n][0] + bv),
                                         f2bf(acc[m][n][1] + bv),
                                         f2bf(acc[m][n][2] + bv),
                                         f2bf(acc[m][n][3] + bv));
                *(ushort4*)&vtb[((size_t)(hh * 64 + dd)) * SEQ + rowm] = u;
            } else {
                const int cc = col - region * 512, hh = cc >> 6, dd = cc & 63;
                unsigned short* dst = (region == 0) ? qb : kb;
                #pragma unroll
                for (int j = 0; j < 4; ++j)
                    dst[((size_t)hh * SEQ + rowm + j) * 64 + dd] =
                        f2bf(acc[m][n][j] + bv);
            }
        }
    }
}

// ---------------------------------------------------------------------------
// MFMA windowed attention (unchanged from round 4).
// ---------------------------------------------------------------------------
__global__ __launch_bounds__(256) void attn_mfma(
    const unsigned short* __restrict__ qb,
    const unsigned short* __restrict__ kb,
    const unsigned short* __restrict__ vtb,
    unsigned short* __restrict__ o)
{
    constexpr float SCALE_L2E = 0.044194173824159216f * 1.4426950408889634f;
    __shared__ __align__(16) unsigned short P_lds[4][16][72];

    const int tid  = threadIdx.x;
    const int lane = tid & 63;
    const int w    = tid >> 6;
    const int i0   = blockIdx.x * 64;
    const int h    = blockIdx.y;
    const int lr = lane & 15, lg = lane >> 4;

    const unsigned short* qh = qb  + (size_t)h * SEQ * 64;
    const unsigned short* kh = kb  + (size_t)h * SEQ * 64;
    const unsigned short* vh = vtb + (size_t)h * 64 * SEQ;

    bf16x8 bq[2];
    {
        const unsigned short* qrow = qh + (size_t)(i0 + w * 16 + lr) * 64 + lg * 8;
        bq[0] = *(const bf16x8*)qrow;
        bq[1] = *(const bf16x8*)(qrow + 32);
    }

    f32x4 accO[4];
    #pragma unroll
    for (int n = 0; n < 4; ++n) accO[n] = f32x4{0.f, 0.f, 0.f, 0.f};
    float lsum = 0.0f;
    const int iq = i0 + w * 16 + lr;

    for (int c = 0; c < 5; ++c) {
        const int j0 = i0 - WIN + c * 64;
        if (j0 < 0 || j0 >= SEQ) continue;

        bf16x8 ak[2][4];
        #pragma unroll
        for (int m = 0; m < 4; ++m) {
            const unsigned short* kr = kh + (size_t)(j0 + m * 16 + lr) * 64 + lg * 8;
            ak[0][m] = *(const bf16x8*)kr;
            ak[1][m] = *(const bf16x8*)(kr + 32);
        }
        bf16x8 bv[2][4];
        #pragma unroll
        for (int n = 0; n < 4; ++n) {
            const unsigned short* vr = vh + (size_t)(n * 16 + lr) * SEQ + j0 + lg * 8;
            bv[0][n] = *(const bf16x8*)vr;
            bv[1][n] = *(const bf16x8*)(vr + 32);
        }

        f32x4 accS[4];
        #pragma unroll
        for (int m = 0; m < 4; ++m) {
            accS[m] = f32x4{0.f, 0.f, 0.f, 0.f};
            #pragma unroll
            for (int s = 0; s < 2; ++s)
                accS[m] = __builtin_amdgcn_mfma_f32_16x16x32_bf16(
                    ak[s][m], bq[s], accS[m], 0, 0, 0);
        }

        #pragma unroll
        for (int m = 0; m < 4; ++m) {
            const int kbase = j0 + m * 16 + lg * 4;
            float p0, p1, p2, p3;
            {
                int d0 = kbase + 0 - iq; bool v0 = (d0 >= -WIN) && (d0 <= WIN);
                int d1 = kbase + 1 - iq; bool v1 = (d1 >= -WIN) && (d1 <= WIN);
                int d2 = kbase + 2 - iq; bool v2 = (d2 >= -WIN) && (d2 <= WIN);
                int d3 = kbase + 3 - iq; bool v3 = (d3 >= -WIN) && (d3 <= WIN);
                p0 = v0 ? exp2f(accS[m][0] * SCALE_L2E) : 0.0f;
                p1 = v1 ? exp2f(accS[m][1] * SCALE_L2E) : 0.0f;
                p2 = v2 ? exp2f(accS[m][2] * SCALE_L2E) : 0.0f;
                p3 = v3 ? exp2f(accS[m][3] * SCALE_L2E) : 0.0f;
            }
            lsum += (p0 + p1) + (p2 + p3);
            ushort4 pk = make_ushort4(f2bf(p0), f2bf(p1), f2bf(p2), f2bf(p3));
            *(ushort4*)&P_lds[w][lr][m * 16 + lg * 4] = pk;
        }

        bf16x8 pa[2];
        pa[0] = *(const bf16x8*)&P_lds[w][lr][lg * 8];
        pa[1] = *(const bf16x8*)&P_lds[w][lr][32 + lg * 8];

        #pragma unroll
        for (int n = 0; n < 4; ++n)
            #pragma unroll
            for (int s = 0; s < 2; ++s)
                accO[n] = __builtin_amdgcn_mfma_f32_16x16x32_bf16(
                    pa[s], bv[s][n], accO[n], 0, 0, 0);
    }

    lsum += __shfl_xor(lsum, 16, 64);
    lsum += __shfl_xor(lsum, 32, 64);
    float rinv[4];
    #pragma unroll
    for (int j = 0; j < 4; ++j)
        rinv[j] = 1.0f / __shfl(lsum, lg * 4 + j, 64);

    #pragma unroll
    for (int n = 0; n < 4; ++n)
        #pragma unroll
        for (int j = 0; j < 4; ++j) {
            int row = i0 + w * 16 + lg * 4 + j;
            int col = h * 64 + n * 16 + lr;
            o[(size_t)row * D + col] = f2bf(accO[n][j] * rinv[j]);
        }
}

// ---------------------------------------------------------------------------
// out = LayerNorm(a + sum_{p<NP} P[p]) * g + beta; optional bf16 copy.
// One wave per 512-elem row.
// ---------------------------------------------------------------------------
template <int NP, bool DUAL>
__global__ __launch_bounds__(256) void add_ln_np(
    const float* __restrict__ a, const float* __restrict__ P, size_t pstride,
    const float* __restrict__ g, const float* __restrict__ beta,
    float* __restrict__ out, unsigned short* __restrict__ outb)
{
    const int wave = threadIdx.x >> 6;
    const int lane = threadIdx.x & 63;
    const int row = blockIdx.x * 4 + wave;

    const float* pa = a + (size_t)row * D;

    float v[8];
    float sum = 0.0f, sumsq = 0.0f;
    #pragma unroll
    for (int e = 0; e < 8; ++e) {
        int c = lane + e * 64;
        float z = pa[c];
        #pragma unroll
        for (int p = 0; p < NP; ++p)
            z += P[p * pstride + (size_t)row * D + c];
        v[e] = z;
        sum += z;
        sumsq += z * z;
    }
    #pragma unroll
    for (int off = 32; off; off >>= 1) {
        sum   += __shfl_xor(sum, off, 64);
        sumsq += __shfl_xor(sumsq, off, 64);
    }
    const float mu   = sum * (1.0f / D);
    const float var  = sumsq * (1.0f / D) - mu * mu;
    const float rstd = rsqrtf(var + LN_EPS);

    float* po = out + (size_t)row * D;
    #pragma unroll
    for (int e = 0; e < 8; ++e) {
        int c = lane + e * 64;
        float r = (v[e] - mu) * rstd * g[c] + beta[c];
        po[c] = r;
        if (DUAL) outb[(size_t)row * D + c] = f2bf(r);
    }
}

// ---------------------------------------------------------------------------
extern "C" void kernel_launch(void* const* d_in, const int* in_sizes, int n_in,
                              void* d_out, int out_size, void* d_ws, size_t ws_size,
                              hipStream_t stream)
{
    const float* x      = (const float*)d_in[0];
    const float* qkv_w  = (const float*)d_in[1];
    const float* qkv_b  = (const float*)d_in[2];
    const float* out_w  = (const float*)d_in[3];
    const float* out_b  = (const float*)d_in[4];
    const float* ln1_g  = (const float*)d_in[5];
    const float* ln1_b  = (const float*)d_in[6];
    const float* w1     = (const float*)d_in[7];
    const float* b1     = (const float*)d_in[8];
    const float* w2     = (const float*)d_in[9];
    const float* b2     = (const float*)d_in[10];
    const float* ln2_g  = (const float*)d_in[11];
    const float* ln2_b  = (const float*)d_in[12];
    float* out = (float*)d_out;

    // ---- workspace layout (explicit offsets, MiB granularity) ----
    // Scratch region [0,44): dead by the time FF2 runs; pFF2 [0,32) aliases it.
    constexpr size_t MiB = 1u << 20;
    char* base = (char*)d_ws;
    unsigned short* xb     = (unsigned short*)(base + 0);          // 4    [0,4)
    unsigned short* qkvw_t = (unsigned short*)(base + 4 * MiB);    // 1.5  [4,5.5)
    unsigned short* outw_t = (unsigned short*)(base + 5 * MiB + 512 * 1024); // 0.5 [5.5,6)
    unsigned short* w1_t   = (unsigned short*)(base + 6 * MiB);    // 2    [6,8)
    unsigned short* qbuf   = (unsigned short*)(base + 8 * MiB);    // 4    [8,12)
    unsigned short* kbuf   = (unsigned short*)(base + 12 * MiB);   // 4    [12,16)
    unsigned short* vtbuf  = (unsigned short*)(base + 16 * MiB);   // 4    [16,20)
    unsigned short* o_b    = (unsigned short*)(base + 20 * MiB);   // 4    [20,24)
    float*          pOut   = (float*)(base + 24 * MiB);            // 16   [24,40)
    unsigned short* x1b    = (unsigned short*)(base + 40 * MiB);   // 4    [40,44)
    float*          pFF2   = (float*)(base + 0);                   // 32   [0,32) alias
    // Long-lived:
    unsigned short* w2_t   = (unsigned short*)(base + 44 * MiB);   // 2    [44,46)
    float*          x1     = (float*)(base + 46 * MiB);            // 8    [46,54)
    unsigned short* ff1b   = (unsigned short*)(base + 54 * MiB);   // 16   [54,70)

    // ---- conversions ----
    f32_to_bf16<<<(SEQ * D) / 1024, 256, 0, stream>>>(x, xb, SEQ * D);
    transpose_all<<<3072, dim3(32, 8), 0, stream>>>(
        qkv_w, out_w, w1, w2, qkvw_t, outw_t, w1_t, w2_t);

    // 1) qkv projection -> qb/kb/vtb
    gemm_qkv<<<dim3(3 * D / 128, SEQ / 128), 256, 0, stream>>>(
        xb, qkvw_t, qkv_b, qbuf, kbuf, vtbuf);

    // 2) MFMA windowed attention -> o bf16
    attn_mfma<<<dim3(SEQ / 64, NH), 256, 0, stream>>>(qbuf, kbuf, vtbuf, o_b);

    // 3) out-proj, split-K 2: partials [2][4096][512]
    gemm_splitk<<<dim3(D / 128, SEQ / 128, 2), 256, 0, stream>>>(
        o_b, outw_t, out_b, pOut, SEQ, D, D, D / 2);

    // 4) x1 = LN(x + p0 + p1) -> fp32 + bf16
    add_ln_np<2, true><<<SEQ / 4, 256, 0, stream>>>(
        x, pOut, (size_t)SEQ * D, ln1_g, ln1_b, x1, x1b);

    // 5) ff1 = relu(x1b @ w1 + b1) -> bf16
    gemm_mfma<true, true><<<dim3(DFF / 128, SEQ / 128), 256, 0, stream>>>(
        x1b, w1_t, b1, ff1b, SEQ, DFF, D);

    // 6) ff2 split-K 4: partials [4][4096][512]
    gemm_splitk<<<dim3(D / 128, SEQ / 128, 4), 256, 0, stream>>>(
        ff1b, w2_t, b2, pFF2, SEQ, D, DFF, DFF / 4);

    // 7) out = LN(x1 + p0+p1+p2+p3)
    add_ln_np<4, false><<<SEQ / 4, 256, 0, stream>>>(
        x1, pFF2, (size_t)SEQ * D, ln2_g, ln2_b, out, nullptr);
}

// Round 6
// 106.099 us; speedup vs baseline: 10.4625x; 1.1431x over previous
//
#include <hip/hip_runtime.h>
#include <math.h>

// Problem constants
constexpr int D      = 512;
constexpr int NH     = 8;
constexpr int HD     = 64;
constexpr int WIN    = 128;
constexpr int DFF    = 2048;
constexpr int SEQ    = 4096;
constexpr float LN_EPS = 1e-5f;

typedef float f32x4 __attribute__((ext_vector_type(4)));
typedef __bf16 bf16x8 __attribute__((ext_vector_type(8)));

__device__ __forceinline__ unsigned short f2bf(float f) {
    union { float f; unsigned u; } v; v.f = f;
    unsigned r = v.u + 0x7FFF + ((v.u >> 16) & 1);   // round-to-nearest-even
    return (unsigned short)(r >> 16);
}
__device__ __forceinline__ float bf2f(unsigned short u) {
    union { unsigned u; float f; } v; v.u = (unsigned)u << 16; return v.f;
}

__device__ __forceinline__ void gload16(const void* g, void* l) {
    __builtin_amdgcn_global_load_lds(
        (const __attribute__((address_space(1))) unsigned int*)g,
        (__attribute__((address_space(3))) unsigned int*)l,
        16, 0, 0);
}

// ---------------------------------------------------------------------------
// prep: block [0,1024)  : x fp32 -> xb bf16 (2048 elems/block)
//       block [1024,4096): weight transposes W[K][N] fp32 -> Wt[N][K] bf16
// ---------------------------------------------------------------------------
__global__ __launch_bounds__(256) void prep(
    const float* __restrict__ x, unsigned short* __restrict__ xb,
    const float* __restrict__ qkv_w, const float* __restrict__ out_w,
    const float* __restrict__ w1,    const float* __restrict__ w2,
    unsigned short* __restrict__ qkvw_t, unsigned short* __restrict__ outw_t,
    unsigned short* __restrict__ w1_t,   unsigned short* __restrict__ w2_t)
{
    const int b = blockIdx.x;
    if (b < 1024) {
        int i = b * 2048 + threadIdx.x * 8;
        float4 v0 = *(const float4*)(x + i);
        float4 v1 = *(const float4*)(x + i + 4);
        ushort4 u0 = make_ushort4(f2bf(v0.x), f2bf(v0.y), f2bf(v0.z), f2bf(v0.w));
        ushort4 u1 = make_ushort4(f2bf(v1.x), f2bf(v1.y), f2bf(v1.z), f2bf(v1.w));
        *(ushort4*)(xb + i) = u0;
        *(ushort4*)(xb + i + 4) = u1;
        return;
    }
    __shared__ float t[32][33];
    const int b2 = b - 1024;
    const float* W; unsigned short* Wt; int K, N, nt, kt;
    if (b2 < 768)       { W = qkv_w; Wt = qkvw_t; K = 512;  N = 1536; nt = b2 % 48;          kt = b2 / 48; }
    else if (b2 < 1024) { W = out_w; Wt = outw_t; K = 512;  N = 512;  nt = (b2 - 768) % 16;  kt = (b2 - 768) / 16; }
    else if (b2 < 2048) { W = w1;    Wt = w1_t;   K = 512;  N = 2048; nt = (b2 - 1024) % 64; kt = (b2 - 1024) / 64; }
    else                { W = w2;    Wt = w2_t;   K = 2048; N = 512;  nt = (b2 - 2048) % 16; kt = (b2 - 2048) / 16; }
    const int tx = threadIdx.x & 31, ty = threadIdx.x >> 5;
    const int n0 = nt * 32, k0 = kt * 32;
    #pragma unroll
    for (int r = 0; r < 4; ++r)
        t[ty + r * 8][tx] = W[(size_t)(k0 + ty + r * 8) * N + n0 + tx];
    __syncthreads();
    #pragma unroll
    for (int r = 0; r < 4; ++r)
        Wt[(size_t)(n0 + ty + r * 8) * K + k0 + tx] = f2bf(t[tx][ty + r * 8]);
}

// ---------------------------------------------------------------------------
// GEMM core, BK=64 staged as 2x BK=32 sub-tiles (identical 64B-pitch layout
// to the m97-style BK=32 version -> same bank profile), one barrier pair per
// 64-deep K-step (32 MFMAs/wave between barriers).
// LDS 32KB: A0 | A1 | B0 | B1, each [128 rows][64B].
// ---------------------------------------------------------------------------
__device__ __forceinline__ void gemm_core64(
    const unsigned short* __restrict__ A, const unsigned short* __restrict__ Bt,
    int K, int m0, int n0, int kbeg, int kend, char* lds, f32x4 acc[4][4])
{
    const int tid  = threadIdx.x;
    const int lane = tid & 63;
    const int wave = tid >> 6;
    const int wr = wave >> 1, wc = wave & 1;
    const int lr = lane & 15, lk = lane >> 4;
    const int aoff = ((wr * 64 + lr) << 6) + (lk << 4);
    const int boff = ((wc * 64 + lr) << 6) + (lk << 4);
    const int srow = (tid * 16) >> 6;      // 0..63
    const int skb  = (tid * 16) & 63;

    for (int k0 = kbeg; k0 < kend; k0 += 64) {
        #pragma unroll
        for (int r = 0; r < 2; ++r) {
            const int row = srow + r * 64;
            const char* pa = (const char*)A + ((size_t)(m0 + row) * K + k0) * 2 + skb;
            const char* pb = (const char*)Bt + ((size_t)(n0 + row) * K + k0) * 2 + skb;
            gload16(pa,      lds +         r * 4096 + tid * 16);   // A, k half 0
            gload16(pa + 64, lds +  8192 + r * 4096 + tid * 16);   // A, k half 1
            gload16(pb,      lds + 16384 + r * 4096 + tid * 16);   // B, k half 0
            gload16(pb + 64, lds + 24576 + r * 4096 + tid * 16);   // B, k half 1
        }
        __syncthreads();

        bf16x8 af[2][4], bfv[2][4];
        #pragma unroll
        for (int m = 0; m < 4; ++m) {
            af[0][m] = *(const bf16x8*)(lds +        aoff + m * 1024);
            af[1][m] = *(const bf16x8*)(lds + 8192 + aoff + m * 1024);
        }
        #pragma unroll
        for (int n = 0; n < 4; ++n) {
            bfv[0][n] = *(const bf16x8*)(lds + 16384 + boff + n * 1024);
            bfv[1][n] = *(const bf16x8*)(lds + 24576 + boff + n * 1024);
        }
        #pragma unroll
        for (int ks = 0; ks < 2; ++ks)
            #pragma unroll
            for (int m = 0; m < 4; ++m)
                #pragma unroll
                for (int n = 0; n < 4; ++n)
                    acc[m][n] = __builtin_amdgcn_mfma_f32_16x16x32_bf16(
                        af[ks][m], bfv[ks][n], acc[m][n], 0, 0, 0);
        __syncthreads();
    }
}

// ---------------------------------------------------------------------------
// Monolithic GEMM + bias (+ReLU), bf16 or fp32 out. 128x128 tile.
// ---------------------------------------------------------------------------
template <bool RELU, bool OUT_BF16>
__global__ __launch_bounds__(256) void gemm_mfma(
    const unsigned short* __restrict__ A,
    const unsigned short* __restrict__ Bt,
    const float* __restrict__ bias,
    void* __restrict__ Cv, int M, int N, int K)
{
    __shared__ __align__(16) char lds[32768];
    const int lane = threadIdx.x & 63;
    const int wave = threadIdx.x >> 6;
    const int wr = wave >> 1, wc = wave & 1;
    const int lr = lane & 15, lk = lane >> 4;
    const int m0 = blockIdx.y * 128, n0 = blockIdx.x * 128;

    f32x4 acc[4][4];
    #pragma unroll
    for (int m = 0; m < 4; ++m)
        #pragma unroll
        for (int n = 0; n < 4; ++n) acc[m][n] = f32x4{0.f, 0.f, 0.f, 0.f};

    gemm_core64(A, Bt, K, m0, n0, 0, K, lds, acc);

    const int col0 = n0 + wc * 64 + lr;
    const int row0 = m0 + wr * 64 + lk * 4;
    #pragma unroll
    for (int m = 0; m < 4; ++m)
        #pragma unroll
        for (int n = 0; n < 4; ++n) {
            int col = col0 + n * 16;
            float bv = bias[col];
            #pragma unroll
            for (int j = 0; j < 4; ++j) {
                int row = row0 + m * 16 + j;
                float v = acc[m][n][j] + bv;
                if (RELU) v = fmaxf(v, 0.0f);
                if (OUT_BF16)
                    ((unsigned short*)Cv)[(size_t)row * N + col] = f2bf(v);
                else
                    ((float*)Cv)[(size_t)row * N + col] = v;
            }
        }
}

// ---------------------------------------------------------------------------
// Split-K GEMM: chunk z covers [z*Kc,(z+1)*Kc); writes bf16 partial to
// P + z*M*N (bias folded into chunk 0). Combined in the following add_ln.
// ---------------------------------------------------------------------------
__global__ __launch_bounds__(256) void gemm_splitk(
    const unsigned short* __restrict__ A,
    const unsigned short* __restrict__ Bt,
    const float* __restrict__ bias,
    unsigned short* __restrict__ P, int M, int N, int K, int Kc)
{
    __shared__ __align__(16) char lds[32768];
    const int lane = threadIdx.x & 63;
    const int wave = threadIdx.x >> 6;
    const int wr = wave >> 1, wc = wave & 1;
    const int lr = lane & 15, lk = lane >> 4;
    const int m0 = blockIdx.y * 128, n0 = blockIdx.x * 128;
    const int zc = blockIdx.z;

    f32x4 acc[4][4];
    #pragma unroll
    for (int m = 0; m < 4; ++m)
        #pragma unroll
        for (int n = 0; n < 4; ++n) acc[m][n] = f32x4{0.f, 0.f, 0.f, 0.f};

    gemm_core64(A, Bt, K, m0, n0, zc * Kc, zc * Kc + Kc, lds, acc);

    unsigned short* Cp = P + (size_t)zc * M * N;
    const int col0 = n0 + wc * 64 + lr;
    const int row0 = m0 + wr * 64 + lk * 4;
    #pragma unroll
    for (int m = 0; m < 4; ++m)
        #pragma unroll
        for (int n = 0; n < 4; ++n) {
            int col = col0 + n * 16;
            float bv = (zc == 0) ? bias[col] : 0.0f;
            #pragma unroll
            for (int j = 0; j < 4; ++j) {
                int row = row0 + m * 16 + j;
                Cp[(size_t)row * N + col] = f2bf(acc[m][n][j] + bv);
            }
        }
}

// ---------------------------------------------------------------------------
// QKV GEMM: attention-layout epilogue. qb/kb [NH][SEQ][64], vtb [NH][64][SEQ].
// ---------------------------------------------------------------------------
__global__ __launch_bounds__(256) void gemm_qkv(
    const unsigned short* __restrict__ A,
    const unsigned short* __restrict__ Bt,
    const float* __restrict__ bias,
    unsigned short* __restrict__ qb,
    unsigned short* __restrict__ kb,
    unsigned short* __restrict__ vtb)
{
    constexpr int N = 3 * D, K = D;
    __shared__ __align__(16) char lds[32768];
    const int lane = threadIdx.x & 63;
    const int wave = threadIdx.x >> 6;
    const int wr = wave >> 1, wc = wave & 1;
    const int lr = lane & 15, lk = lane >> 4;
    const int m0 = blockIdx.y * 128, n0 = blockIdx.x * 128;

    f32x4 acc[4][4];
    #pragma unroll
    for (int m = 0; m < 4; ++m)
        #pragma unroll
        for (int n = 0; n < 4; ++n) acc[m][n] = f32x4{0.f, 0.f, 0.f, 0.f};

    gemm_core64(A, Bt, K, m0, n0, 0, K, lds, acc);

    const int col0 = n0 + wc * 64 + lr;
    const int row0 = m0 + wr * 64 + lk * 4;
    const int region = n0 >> 9;   // 0=Q, 1=K, 2=V (uniform per block)
    #pragma unroll
    for (int m = 0; m < 4; ++m)
        #pragma unroll
        for (int n = 0; n < 4; ++n) {
            const int col = col0 + n * 16;
            const float bv = bias[col];
            const int rowm = row0 + m * 16;
            if (region == 2) {
                const int cc = col - 1024, hh = cc >> 6, dd = cc & 63;
                ushort4 u = make_ushort4(f2bf(acc[m][n][0] + bv),
                                         f2bf(acc[m][n][1] + bv),
                                         f2bf(acc[m][n][2] + bv),
                                         f2bf(acc[m][n][3] + bv));
                *(ushort4*)&vtb[((size_t)(hh * 64 + dd)) * SEQ + rowm] = u;
            } else {
                const int cc = col - region * 512, hh = cc >> 6, dd = cc & 63;
                unsigned short* dst = (region == 0) ? qb : kb;
                #pragma unroll
                for (int j = 0; j < 4; ++j)
                    dst[((size_t)hh * SEQ + rowm + j) * 64 + dd] =
                        f2bf(acc[m][n][j] + bv);
            }
        }
}

// ---------------------------------------------------------------------------
// MFMA windowed attention (unchanged).
// ---------------------------------------------------------------------------
__global__ __launch_bounds__(256) void attn_mfma(
    const unsigned short* __restrict__ qb,
    const unsigned short* __restrict__ kb,
    const unsigned short* __restrict__ vtb,
    unsigned short* __restrict__ o)
{
    constexpr float SCALE_L2E = 0.044194173824159216f * 1.4426950408889634f;
    __shared__ __align__(16) unsigned short P_lds[4][16][72];

    const int lane = threadIdx.x & 63;
    const int w    = threadIdx.x >> 6;
    const int i0   = blockIdx.x * 64;
    const int h    = blockIdx.y;
    const int lr = lane & 15, lg = lane >> 4;

    const unsigned short* qh = qb  + (size_t)h * SEQ * 64;
    const unsigned short* kh = kb  + (size_t)h * SEQ * 64;
    const unsigned short* vh = vtb + (size_t)h * 64 * SEQ;

    bf16x8 bq[2];
    {
        const unsigned short* qrow = qh + (size_t)(i0 + w * 16 + lr) * 64 + lg * 8;
        bq[0] = *(const bf16x8*)qrow;
        bq[1] = *(const bf16x8*)(qrow + 32);
    }

    f32x4 accO[4];
    #pragma unroll
    for (int n = 0; n < 4; ++n) accO[n] = f32x4{0.f, 0.f, 0.f, 0.f};
    float lsum = 0.0f;
    const int iq = i0 + w * 16 + lr;

    for (int c = 0; c < 5; ++c) {
        const int j0 = i0 - WIN + c * 64;
        if (j0 < 0 || j0 >= SEQ) continue;

        bf16x8 ak[2][4];
        #pragma unroll
        for (int m = 0; m < 4; ++m) {
            const unsigned short* kr = kh + (size_t)(j0 + m * 16 + lr) * 64 + lg * 8;
            ak[0][m] = *(const bf16x8*)kr;
            ak[1][m] = *(const bf16x8*)(kr + 32);
        }
        bf16x8 bv[2][4];
        #pragma unroll
        for (int n = 0; n < 4; ++n) {
            const unsigned short* vr = vh + (size_t)(n * 16 + lr) * SEQ + j0 + lg * 8;
            bv[0][n] = *(const bf16x8*)vr;
            bv[1][n] = *(const bf16x8*)(vr + 32);
        }

        f32x4 accS[4];
        #pragma unroll
        for (int m = 0; m < 4; ++m) {
            accS[m] = f32x4{0.f, 0.f, 0.f, 0.f};
            #pragma unroll
            for (int s = 0; s < 2; ++s)
                accS[m] = __builtin_amdgcn_mfma_f32_16x16x32_bf16(
                    ak[s][m], bq[s], accS[m], 0, 0, 0);
        }

        #pragma unroll
        for (int m = 0; m < 4; ++m) {
            const int kbase = j0 + m * 16 + lg * 4;
            float p0, p1, p2, p3;
            {
                int d0 = kbase + 0 - iq; bool v0 = (d0 >= -WIN) && (d0 <= WIN);
                int d1 = kbase + 1 - iq; bool v1 = (d1 >= -WIN) && (d1 <= WIN);
                int d2 = kbase + 2 - iq; bool v2 = (d2 >= -WIN) && (d2 <= WIN);
                int d3 = kbase + 3 - iq; bool v3 = (d3 >= -WIN) && (d3 <= WIN);
                p0 = v0 ? exp2f(accS[m][0] * SCALE_L2E) : 0.0f;
                p1 = v1 ? exp2f(accS[m][1] * SCALE_L2E) : 0.0f;
                p2 = v2 ? exp2f(accS[m][2] * SCALE_L2E) : 0.0f;
                p3 = v3 ? exp2f(accS[m][3] * SCALE_L2E) : 0.0f;
            }
            lsum += (p0 + p1) + (p2 + p3);
            ushort4 pk = make_ushort4(f2bf(p0), f2bf(p1), f2bf(p2), f2bf(p3));
            *(ushort4*)&P_lds[w][lr][m * 16 + lg * 4] = pk;
        }

        bf16x8 pa[2];
        pa[0] = *(const bf16x8*)&P_lds[w][lr][lg * 8];
        pa[1] = *(const bf16x8*)&P_lds[w][lr][32 + lg * 8];

        #pragma unroll
        for (int n = 0; n < 4; ++n)
            #pragma unroll
            for (int s = 0; s < 2; ++s)
                accO[n] = __builtin_amdgcn_mfma_f32_16x16x32_bf16(
                    pa[s], bv[s][n], accO[n], 0, 0, 0);
    }

    lsum += __shfl_xor(lsum, 16, 64);
    lsum += __shfl_xor(lsum, 32, 64);
    float rinv[4];
    #pragma unroll
    for (int j = 0; j < 4; ++j)
        rinv[j] = 1.0f / __shfl(lsum, lg * 4 + j, 64);

    #pragma unroll
    for (int n = 0; n < 4; ++n)
        #pragma unroll
        for (int j = 0; j < 4; ++j) {
            int row = i0 + w * 16 + lg * 4 + j;
            int col = h * 64 + n * 16 + lr;
            o[(size_t)row * D + col] = f2bf(accO[n][j] * rinv[j]);
        }
}

// ---------------------------------------------------------------------------
// out = LayerNorm(residual + sum_{p<NP} P_bf16[p]) * g + beta.
// RES_BF16: residual is bf16 (else fp32). OUT_BF16: out is bf16 (else fp32).
// One wave per 512-elem row.
// ---------------------------------------------------------------------------
template <int NP, bool RES_BF16, bool OUT_BF16>
__global__ __launch_bounds__(256) void add_ln(
    const void* __restrict__ res, const unsigned short* __restrict__ P,
    size_t pstride,
    const float* __restrict__ g, const float* __restrict__ beta,
    void* __restrict__ out)
{
    const int wave = threadIdx.x >> 6;
    const int lane = threadIdx.x & 63;
    const int row = blockIdx.x * 4 + wave;
    const size_t rbase = (size_t)row * D;

    float v[8];
    float sum = 0.0f, sumsq = 0.0f;
    #pragma unroll
    for (int e = 0; e < 8; ++e) {
        int c = lane + e * 64;
        float z = RES_BF16 ? bf2f(((const unsigned short*)res)[rbase + c])
                           : ((const float*)res)[rbase + c];
        #pragma unroll
        for (int p = 0; p < NP; ++p)
            z += bf2f(P[p * pstride + rbase + c]);
        v[e] = z;
        sum += z;
        sumsq += z * z;
    }
    #pragma unroll
    for (int off = 32; off; off >>= 1) {
        sum   += __shfl_xor(sum, off, 64);
        sumsq += __shfl_xor(sumsq, off, 64);
    }
    const float mu   = sum * (1.0f / D);
    const float var  = sumsq * (1.0f / D) - mu * mu;
    const float rstd = rsqrtf(var + LN_EPS);

    #pragma unroll
    for (int e = 0; e < 8; ++e) {
        int c = lane + e * 64;
        float r = (v[e] - mu) * rstd * g[c] + beta[c];
        if (OUT_BF16) ((unsigned short*)out)[rbase + c] = f2bf(r);
        else          ((float*)out)[rbase + c] = r;
    }
}

// ---------------------------------------------------------------------------
extern "C" void kernel_launch(void* const* d_in, const int* in_sizes, int n_in,
                              void* d_out, int out_size, void* d_ws, size_t ws_size,
                              hipStream_t stream)
{
    const float* x      = (const float*)d_in[0];
    const float* qkv_w  = (const float*)d_in[1];
    const float* qkv_b  = (const float*)d_in[2];
    const float* out_w  = (const float*)d_in[3];
    const float* out_b  = (const float*)d_in[4];
    const float* ln1_g  = (const float*)d_in[5];
    const float* ln1_b  = (const float*)d_in[6];
    const float* w1     = (const float*)d_in[7];
    const float* b1     = (const float*)d_in[8];
    const float* w2     = (const float*)d_in[9];
    const float* b2     = (const float*)d_in[10];
    const float* ln2_g  = (const float*)d_in[11];
    const float* ln2_b  = (const float*)d_in[12];
    float* out = (float*)d_out;

    // ---- workspace layout (flat, no aliasing; 70 MiB total) ----
    constexpr size_t MiB = 1u << 20;
    char* base = (char*)d_ws;
    unsigned short* xb     = (unsigned short*)(base + 0);                     // 4
    unsigned short* qkvw_t = (unsigned short*)(base + 4 * MiB);               // 1.5
    unsigned short* outw_t = (unsigned short*)(base + 5 * MiB + 512 * 1024);  // 0.5
    unsigned short* w1_t   = (unsigned short*)(base + 6 * MiB);               // 2
    unsigned short* w2_t   = (unsigned short*)(base + 8 * MiB);               // 2
    unsigned short* qbuf   = (unsigned short*)(base + 10 * MiB);              // 4
    unsigned short* kbuf   = (unsigned short*)(base + 14 * MiB);              // 4
    unsigned short* vtbuf  = (unsigned short*)(base + 18 * MiB);              // 4
    unsigned short* o_b    = (unsigned short*)(base + 22 * MiB);              // 4
    unsigned short* pOut   = (unsigned short*)(base + 26 * MiB);              // 8  (2 partials)
    unsigned short* x1b    = (unsigned short*)(base + 34 * MiB);              // 4
    unsigned short* ff1b   = (unsigned short*)(base + 38 * MiB);              // 16
    unsigned short* pFF2   = (unsigned short*)(base + 54 * MiB);              // 16 (4 partials)

    // 0) conversions + weight transposes (one kernel)
    prep<<<4096, 256, 0, stream>>>(x, xb, qkv_w, out_w, w1, w2,
                                   qkvw_t, outw_t, w1_t, w2_t);

    // 1) qkv projection -> qb/kb/vtb (BK=64)
    gemm_qkv<<<dim3(3 * D / 128, SEQ / 128), 256, 0, stream>>>(
        xb, qkvw_t, qkv_b, qbuf, kbuf, vtbuf);

    // 2) MFMA windowed attention -> o bf16
    attn_mfma<<<dim3(SEQ / 64, NH), 256, 0, stream>>>(qbuf, kbuf, vtbuf, o_b);

    // 3) out-proj, split-K 2 -> bf16 partials
    gemm_splitk<<<dim3(D / 128, SEQ / 128, 2), 256, 0, stream>>>(
        o_b, outw_t, out_b, pOut, SEQ, D, D, D / 2);

    // 4) x1b = bf16( LN(x + p0 + p1) )
    add_ln<2, false, true><<<SEQ / 4, 256, 0, stream>>>(
        x, pOut, (size_t)SEQ * D, ln1_g, ln1_b, x1b);

    // 5) ff1 = relu(x1b @ w1 + b1) -> bf16
    gemm_mfma<true, true><<<dim3(DFF / 128, SEQ / 128), 256, 0, stream>>>(
        x1b, w1_t, b1, ff1b, SEQ, DFF, D);

    // 6) ff2 split-K 4 -> bf16 partials
    gemm_splitk<<<dim3(D / 128, SEQ / 128, 4), 256, 0, stream>>>(
        ff1b, w2_t, b2, pFF2, SEQ, D, DFF, DFF / 4);

    // 7) out = LN(x1b + p0+p1+p2+p3) -> fp32
    add_ln<4, true, false><<<SEQ / 4, 256, 0, stream>>>(
        x1b, pFF2, (size_t)SEQ * D, ln2_g, ln2_b, out);
}

// Round 7
// 99.270 us; speedup vs baseline: 11.1822x; 1.0688x over previous
//
#include <hip/hip_runtime.h>
#include <math.h>

// Problem constants
constexpr int D      = 512;
constexpr int NH     = 8;
constexpr int HD     = 64;
constexpr int WIN    = 128;
constexpr int DFF    = 2048;
constexpr int SEQ    = 4096;
constexpr float LN_EPS = 1e-5f;

typedef float f32x4 __attribute__((ext_vector_type(4)));
typedef __bf16 bf16x8 __attribute__((ext_vector_type(8)));

__device__ __forceinline__ unsigned short f2bf(float f) {
    union { float f; unsigned u; } v; v.f = f;
    unsigned r = v.u + 0x7FFF + ((v.u >> 16) & 1);   // round-to-nearest-even
    return (unsigned short)(r >> 16);
}
__device__ __forceinline__ float bf2f(unsigned short u) {
    union { unsigned u; float f; } v; v.u = (unsigned)u << 16; return v.f;
}

__device__ __forceinline__ void gload16(const void* g, void* l) {
    __builtin_amdgcn_global_load_lds(
        (const __attribute__((address_space(1))) unsigned int*)g,
        (__attribute__((address_space(3))) unsigned int*)l,
        16, 0, 0);
}

// ---------------------------------------------------------------------------
// prep: block [0,1024)  : x fp32 -> xb bf16 (2048 elems/block)
//       block [1024,4096): weight transposes W[K][N] fp32 -> Wt[N][K] bf16
// ---------------------------------------------------------------------------
__global__ __launch_bounds__(256) void prep(
    const float* __restrict__ x, unsigned short* __restrict__ xb,
    const float* __restrict__ qkv_w, const float* __restrict__ out_w,
    const float* __restrict__ w1,    const float* __restrict__ w2,
    unsigned short* __restrict__ qkvw_t, unsigned short* __restrict__ outw_t,
    unsigned short* __restrict__ w1_t,   unsigned short* __restrict__ w2_t)
{
    const int b = blockIdx.x;
    if (b < 1024) {
        int i = b * 2048 + threadIdx.x * 8;
        float4 v0 = *(const float4*)(x + i);
        float4 v1 = *(const float4*)(x + i + 4);
        ushort4 u0 = make_ushort4(f2bf(v0.x), f2bf(v0.y), f2bf(v0.z), f2bf(v0.w));
        ushort4 u1 = make_ushort4(f2bf(v1.x), f2bf(v1.y), f2bf(v1.z), f2bf(v1.w));
        *(ushort4*)(xb + i) = u0;
        *(ushort4*)(xb + i + 4) = u1;
        return;
    }
    __shared__ float t[32][33];
    const int b2 = b - 1024;
    const float* W; unsigned short* Wt; int K, N, nt, kt;
    if (b2 < 768)       { W = qkv_w; Wt = qkvw_t; K = 512;  N = 1536; nt = b2 % 48;          kt = b2 / 48; }
    else if (b2 < 1024) { W = out_w; Wt = outw_t; K = 512;  N = 512;  nt = (b2 - 768) % 16;  kt = (b2 - 768) / 16; }
    else if (b2 < 2048) { W = w1;    Wt = w1_t;   K = 512;  N = 2048; nt = (b2 - 1024) % 64; kt = (b2 - 1024) / 64; }
    else                { W = w2;    Wt = w2_t;   K = 2048; N = 512;  nt = (b2 - 2048) % 16; kt = (b2 - 2048) / 16; }
    const int tx = threadIdx.x & 31, ty = threadIdx.x >> 5;
    const int n0 = nt * 32, k0 = kt * 32;
    #pragma unroll
    for (int r = 0; r < 4; ++r)
        t[ty + r * 8][tx] = W[(size_t)(k0 + ty + r * 8) * N + n0 + tx];
    __syncthreads();
    #pragma unroll
    for (int r = 0; r < 4; ++r)
        Wt[(size_t)(n0 + ty + r * 8) * K + k0 + tx] = f2bf(t[tx][ty + r * 8]);
}

// ---------------------------------------------------------------------------
// Stage one BK=64 tile (A 128 rows + B 128 rows, 64B of K-bytes each) into
// one 32KB LDS buffer via global_load_lds width=16.
// Layout within buf: A0 | A1 | B0 | B1, each [64 rows][64B] sub-tiles.
// ---------------------------------------------------------------------------
__device__ __forceinline__ void stage64(
    const unsigned short* __restrict__ A, const unsigned short* __restrict__ Bt,
    int K, int m0, int n0, int k0, char* buf, int srow, int skb, int tid)
{
    #pragma unroll
    for (int r = 0; r < 2; ++r) {
        const int row = srow + r * 64;
        const char* pa = (const char*)A  + ((size_t)(m0 + row) * K + k0) * 2 + skb;
        const char* pb = (const char*)Bt + ((size_t)(n0 + row) * K + k0) * 2 + skb;
        gload16(pa,      buf +         r * 4096 + tid * 16);   // A, k half 0
        gload16(pa + 64, buf +  8192 + r * 4096 + tid * 16);   // A, k half 1
        gload16(pb,      buf + 16384 + r * 4096 + tid * 16);   // B, k half 0
        gload16(pb + 64, buf + 24576 + r * 4096 + tid * 16);   // B, k half 1
    }
}

// ---------------------------------------------------------------------------
// GEMM core, BK=64, 2-phase double-buffered (T3 minimum recipe):
//   prologue: STAGE(buf0) ; __syncthreads (vmcnt0+barrier)
//   iter:     STAGE(buf^1, k+64) ; ds_read frags(buf) ; 32 MFMA ;
//             __syncthreads  (drains next-tile loads under this iter's compute)
// One barrier per K-step; stage latency hidden under ds_read+MFMA.
// LDS: 2 x 32KB buffers.
// ---------------------------------------------------------------------------
__device__ __forceinline__ void gemm_core_db(
    const unsigned short* __restrict__ A, const unsigned short* __restrict__ Bt,
    int K, int m0, int n0, int kbeg, int kend, char* lds, f32x4 acc[4][4])
{
    const int tid  = threadIdx.x;
    const int lane = tid & 63;
    const int wave = tid >> 6;
    const int wr = wave >> 1, wc = wave & 1;
    const int lr = lane & 15, lk = lane >> 4;
    const int aoff = ((wr * 64 + lr) << 6) + (lk << 4);
    const int boff = ((wc * 64 + lr) << 6) + (lk << 4);
    const int srow = (tid * 16) >> 6;      // 0..63
    const int skb  = (tid * 16) & 63;

    stage64(A, Bt, K, m0, n0, kbeg, lds, srow, skb, tid);
    __syncthreads();

    int cur = 0;
    for (int k0 = kbeg; k0 < kend; k0 += 64) {
        char* bufc = lds + cur * 32768;
        if (k0 + 64 < kend)
            stage64(A, Bt, K, m0, n0, k0 + 64, lds + (cur ^ 1) * 32768,
                    srow, skb, tid);

        bf16x8 af[2][4], bfv[2][4];
        #pragma unroll
        for (int m = 0; m < 4; ++m) {
            af[0][m] = *(const bf16x8*)(bufc +        aoff + m * 1024);
            af[1][m] = *(const bf16x8*)(bufc + 8192 + aoff + m * 1024);
        }
        #pragma unroll
        for (int n = 0; n < 4; ++n) {
            bfv[0][n] = *(const bf16x8*)(bufc + 16384 + boff + n * 1024);
            bfv[1][n] = *(const bf16x8*)(bufc + 24576 + boff + n * 1024);
        }
        #pragma unroll
        for (int ks = 0; ks < 2; ++ks)
            #pragma unroll
            for (int m = 0; m < 4; ++m)
                #pragma unroll
                for (int n = 0; n < 4; ++n)
                    acc[m][n] = __builtin_amdgcn_mfma_f32_16x16x32_bf16(
                        af[ks][m], bfv[ks][n], acc[m][n], 0, 0, 0);

        __syncthreads();   // drains this iter's prefetch; buf swap safe
        cur ^= 1;
    }
}

// ---------------------------------------------------------------------------
// Monolithic GEMM + bias (+ReLU), bf16 or fp32 out. 128x128 tile.
// ---------------------------------------------------------------------------
template <bool RELU, bool OUT_BF16>
__global__ __launch_bounds__(256) void gemm_mfma(
    const unsigned short* __restrict__ A,
    const unsigned short* __restrict__ Bt,
    const float* __restrict__ bias,
    void* __restrict__ Cv, int M, int N, int K)
{
    __shared__ __align__(16) char lds[65536];
    const int lane = threadIdx.x & 63;
    const int wave = threadIdx.x >> 6;
    const int wr = wave >> 1, wc = wave & 1;
    const int lr = lane & 15, lk = lane >> 4;
    const int m0 = blockIdx.y * 128, n0 = blockIdx.x * 128;

    f32x4 acc[4][4];
    #pragma unroll
    for (int m = 0; m < 4; ++m)
        #pragma unroll
        for (int n = 0; n < 4; ++n) acc[m][n] = f32x4{0.f, 0.f, 0.f, 0.f};

    gemm_core_db(A, Bt, K, m0, n0, 0, K, lds, acc);

    const int col0 = n0 + wc * 64 + lr;
    const int row0 = m0 + wr * 64 + lk * 4;
    #pragma unroll
    for (int m = 0; m < 4; ++m)
        #pragma unroll
        for (int n = 0; n < 4; ++n) {
            int col = col0 + n * 16;
            float bv = bias[col];
            #pragma unroll
            for (int j = 0; j < 4; ++j) {
                int row = row0 + m * 16 + j;
                float v = acc[m][n][j] + bv;
                if (RELU) v = fmaxf(v, 0.0f);
                if (OUT_BF16)
                    ((unsigned short*)Cv)[(size_t)row * N + col] = f2bf(v);
                else
                    ((float*)Cv)[(size_t)row * N + col] = v;
            }
        }
}

// ---------------------------------------------------------------------------
// Split-K GEMM: chunk z covers [z*Kc,(z+1)*Kc); writes bf16 partial to
// P + z*M*N (bias folded into chunk 0). Combined in the following add_ln.
// ---------------------------------------------------------------------------
__global__ __launch_bounds__(256) void gemm_splitk(
    const unsigned short* __restrict__ A,
    const unsigned short* __restrict__ Bt,
    const float* __restrict__ bias,
    unsigned short* __restrict__ P, int M, int N, int K, int Kc)
{
    __shared__ __align__(16) char lds[65536];
    const int lane = threadIdx.x & 63;
    const int wave = threadIdx.x >> 6;
    const int wr = wave >> 1, wc = wave & 1;
    const int lr = lane & 15, lk = lane >> 4;
    const int m0 = blockIdx.y * 128, n0 = blockIdx.x * 128;
    const int zc = blockIdx.z;

    f32x4 acc[4][4];
    #pragma unroll
    for (int m = 0; m < 4; ++m)
        #pragma unroll
        for (int n = 0; n < 4; ++n) acc[m][n] = f32x4{0.f, 0.f, 0.f, 0.f};

    gemm_core_db(A, Bt, K, m0, n0, zc * Kc, zc * Kc + Kc, lds, acc);

    unsigned short* Cp = P + (size_t)zc * M * N;
    const int col0 = n0 + wc * 64 + lr;
    const int row0 = m0 + wr * 64 + lk * 4;
    #pragma unroll
    for (int m = 0; m < 4; ++m)
        #pragma unroll
        for (int n = 0; n < 4; ++n) {
            int col = col0 + n * 16;
            float bv = (zc == 0) ? bias[col] : 0.0f;
            #pragma unroll
            for (int j = 0; j < 4; ++j) {
                int row = row0 + m * 16 + j;
                Cp[(size_t)row * N + col] = f2bf(acc[m][n][j] + bv);
            }
        }
}

// ---------------------------------------------------------------------------
// QKV GEMM: attention-layout epilogue. qb/kb [NH][SEQ][64], vtb [NH][64][SEQ].
// ---------------------------------------------------------------------------
__global__ __launch_bounds__(256) void gemm_qkv(
    const unsigned short* __restrict__ A,
    const unsigned short* __restrict__ Bt,
    const float* __restrict__ bias,
    unsigned short* __restrict__ qb,
    unsigned short* __restrict__ kb,
    unsigned short* __restrict__ vtb)
{
    constexpr int N = 3 * D, K = D;
    __shared__ __align__(16) char lds[65536];
    const int lane = threadIdx.x & 63;
    const int wave = threadIdx.x >> 6;
    const int wr = wave >> 1, wc = wave & 1;
    const int lr = lane & 15, lk = lane >> 4;
    const int m0 = blockIdx.y * 128, n0 = blockIdx.x * 128;

    f32x4 acc[4][4];
    #pragma unroll
    for (int m = 0; m < 4; ++m)
        #pragma unroll
        for (int n = 0; n < 4; ++n) acc[m][n] = f32x4{0.f, 0.f, 0.f, 0.f};

    gemm_core_db(A, Bt, K, m0, n0, 0, K, lds, acc);

    const int col0 = n0 + wc * 64 + lr;
    const int row0 = m0 + wr * 64 + lk * 4;
    const int region = n0 >> 9;   // 0=Q, 1=K, 2=V (uniform per block)
    #pragma unroll
    for (int m = 0; m < 4; ++m)
        #pragma unroll
        for (int n = 0; n < 4; ++n) {
            const int col = col0 + n * 16;
            const float bv = bias[col];
            const int rowm = row0 + m * 16;
            if (region == 2) {
                const int cc = col - 1024, hh = cc >> 6, dd = cc & 63;
                ushort4 u = make_ushort4(f2bf(acc[m][n][0] + bv),
                                         f2bf(acc[m][n][1] + bv),
                                         f2bf(acc[m][n][2] + bv),
                                         f2bf(acc[m][n][3] + bv));
                *(ushort4*)&vtb[((size_t)(hh * 64 + dd)) * SEQ + rowm] = u;
            } else {
                const int cc = col - region * 512, hh = cc >> 6, dd = cc & 63;
                unsigned short* dst = (region == 0) ? qb : kb;
                #pragma unroll
                for (int j = 0; j < 4; ++j)
                    dst[((size_t)hh * SEQ + rowm + j) * 64 + dd] =
                        f2bf(acc[m][n][j] + bv);
            }
        }
}

// ---------------------------------------------------------------------------
// MFMA windowed attention (unchanged).
// ---------------------------------------------------------------------------
__global__ __launch_bounds__(256) void attn_mfma(
    const unsigned short* __restrict__ qb,
    const unsigned short* __restrict__ kb,
    const unsigned short* __restrict__ vtb,
    unsigned short* __restrict__ o)
{
    constexpr float SCALE_L2E = 0.044194173824159216f * 1.4426950408889634f;
    __shared__ __align__(16) unsigned short P_lds[4][16][72];

    const int lane = threadIdx.x & 63;
    const int w    = threadIdx.x >> 6;
    const int i0   = blockIdx.x * 64;
    const int h    = blockIdx.y;
    const int lr = lane & 15, lg = lane >> 4;

    const unsigned short* qh = qb  + (size_t)h * SEQ * 64;
    const unsigned short* kh = kb  + (size_t)h * SEQ * 64;
    const unsigned short* vh = vtb + (size_t)h * 64 * SEQ;

    bf16x8 bq[2];
    {
        const unsigned short* qrow = qh + (size_t)(i0 + w * 16 + lr) * 64 + lg * 8;
        bq[0] = *(const bf16x8*)qrow;
        bq[1] = *(const bf16x8*)(qrow + 32);
    }

    f32x4 accO[4];
    #pragma unroll
    for (int n = 0; n < 4; ++n) accO[n] = f32x4{0.f, 0.f, 0.f, 0.f};
    float lsum = 0.0f;
    const int iq = i0 + w * 16 + lr;

    for (int c = 0; c < 5; ++c) {
        const int j0 = i0 - WIN + c * 64;
        if (j0 < 0 || j0 >= SEQ) continue;

        bf16x8 ak[2][4];
        #pragma unroll
        for (int m = 0; m < 4; ++m) {
            const unsigned short* kr = kh + (size_t)(j0 + m * 16 + lr) * 64 + lg * 8;
            ak[0][m] = *(const bf16x8*)kr;
            ak[1][m] = *(const bf16x8*)(kr + 32);
        }
        bf16x8 bv[2][4];
        #pragma unroll
        for (int n = 0; n < 4; ++n) {
            const unsigned short* vr = vh + (size_t)(n * 16 + lr) * SEQ + j0 + lg * 8;
            bv[0][n] = *(const bf16x8*)vr;
            bv[1][n] = *(const bf16x8*)(vr + 32);
        }

        f32x4 accS[4];
        #pragma unroll
        for (int m = 0; m < 4; ++m) {
            accS[m] = f32x4{0.f, 0.f, 0.f, 0.f};
            #pragma unroll
            for (int s = 0; s < 2; ++s)
                accS[m] = __builtin_amdgcn_mfma_f32_16x16x32_bf16(
                    ak[s][m], bq[s], accS[m], 0, 0, 0);
        }

        #pragma unroll
        for (int m = 0; m < 4; ++m) {
            const int kbase = j0 + m * 16 + lg * 4;
            float p0, p1, p2, p3;
            {
                int d0 = kbase + 0 - iq; bool v0 = (d0 >= -WIN) && (d0 <= WIN);
                int d1 = kbase + 1 - iq; bool v1 = (d1 >= -WIN) && (d1 <= WIN);
                int d2 = kbase + 2 - iq; bool v2 = (d2 >= -WIN) && (d2 <= WIN);
                int d3 = kbase + 3 - iq; bool v3 = (d3 >= -WIN) && (d3 <= WIN);
                p0 = v0 ? exp2f(accS[m][0] * SCALE_L2E) : 0.0f;
                p1 = v1 ? exp2f(accS[m][1] * SCALE_L2E) : 0.0f;
                p2 = v2 ? exp2f(accS[m][2] * SCALE_L2E) : 0.0f;
                p3 = v3 ? exp2f(accS[m][3] * SCALE_L2E) : 0.0f;
            }
            lsum += (p0 + p1) + (p2 + p3);
            ushort4 pk = make_ushort4(f2bf(p0), f2bf(p1), f2bf(p2), f2bf(p3));
            *(ushort4*)&P_lds[w][lr][m * 16 + lg * 4] = pk;
        }

        bf16x8 pa[2];
        pa[0] = *(const bf16x8*)&P_lds[w][lr][lg * 8];
        pa[1] = *(const bf16x8*)&P_lds[w][lr][32 + lg * 8];

        #pragma unroll
        for (int n = 0; n < 4; ++n)
            #pragma unroll
            for (int s = 0; s < 2; ++s)
                accO[n] = __builtin_amdgcn_mfma_f32_16x16x32_bf16(
                    pa[s], bv[s][n], accO[n], 0, 0, 0);
    }

    lsum += __shfl_xor(lsum, 16, 64);
    lsum += __shfl_xor(lsum, 32, 64);
    float rinv[4];
    #pragma unroll
    for (int j = 0; j < 4; ++j)
        rinv[j] = 1.0f / __shfl(lsum, lg * 4 + j, 64);

    #pragma unroll
    for (int n = 0; n < 4; ++n)
        #pragma unroll
        for (int j = 0; j < 4; ++j) {
            int row = i0 + w * 16 + lg * 4 + j;
            int col = h * 64 + n * 16 + lr;
            o[(size_t)row * D + col] = f2bf(accO[n][j] * rinv[j]);
        }
}

// ---------------------------------------------------------------------------
// out = LayerNorm(residual + sum_{p<NP} P_bf16[p]) * g + beta.
// ---------------------------------------------------------------------------
template <int NP, bool RES_BF16, bool OUT_BF16>
__global__ __launch_bounds__(256) void add_ln(
    const void* __restrict__ res, const unsigned short* __restrict__ P,
    size_t pstride,
    const float* __restrict__ g, const float* __restrict__ beta,
    void* __restrict__ out)
{
    const int wave = threadIdx.x >> 6;
    const int lane = threadIdx.x & 63;
    const int row = blockIdx.x * 4 + wave;
    const size_t rbase = (size_t)row * D;

    float v[8];
    float sum = 0.0f, sumsq = 0.0f;
    #pragma unroll
    for (int e = 0; e < 8; ++e) {
        int c = lane + e * 64;
        float z = RES_BF16 ? bf2f(((const unsigned short*)res)[rbase + c])
                           : ((const float*)res)[rbase + c];
        #pragma unroll
        for (int p = 0; p < NP; ++p)
            z += bf2f(P[p * pstride + rbase + c]);
        v[e] = z;
        sum += z;
        sumsq += z * z;
    }
    #pragma unroll
    for (int off = 32; off; off >>= 1) {
        sum   += __shfl_xor(sum, off, 64);
        sumsq += __shfl_xor(sumsq, off, 64);
    }
    const float mu   = sum * (1.0f / D);
    const float var  = sumsq * (1.0f / D) - mu * mu;
    const float rstd = rsqrtf(var + LN_EPS);

    #pragma unroll
    for (int e = 0; e < 8; ++e) {
        int c = lane + e * 64;
        float r = (v[e] - mu) * rstd * g[c] + beta[c];
        if (OUT_BF16) ((unsigned short*)out)[rbase + c] = f2bf(r);
        else          ((float*)out)[rbase + c] = r;
    }
}

// ---------------------------------------------------------------------------
extern "C" void kernel_launch(void* const* d_in, const int* in_sizes, int n_in,
                              void* d_out, int out_size, void* d_ws, size_t ws_size,
                              hipStream_t stream)
{
    const float* x      = (const float*)d_in[0];
    const float* qkv_w  = (const float*)d_in[1];
    const float* qkv_b  = (const float*)d_in[2];
    const float* out_w  = (const float*)d_in[3];
    const float* out_b  = (const float*)d_in[4];
    const float* ln1_g  = (const float*)d_in[5];
    const float* ln1_b  = (const float*)d_in[6];
    const float* w1     = (const float*)d_in[7];
    const float* b1     = (const float*)d_in[8];
    const float* w2     = (const float*)d_in[9];
    const float* b2     = (const float*)d_in[10];
    const float* ln2_g  = (const float*)d_in[11];
    const float* ln2_b  = (const float*)d_in[12];
    float* out = (float*)d_out;

    // ---- workspace layout (flat, no aliasing; 70 MiB total) ----
    constexpr size_t MiB = 1u << 20;
    char* base = (char*)d_ws;
    unsigned short* xb     = (unsigned short*)(base + 0);                     // 4
    unsigned short* qkvw_t = (unsigned short*)(base + 4 * MiB);               // 1.5
    unsigned short* outw_t = (unsigned short*)(base + 5 * MiB + 512 * 1024);  // 0.5
    unsigned short* w1_t   = (unsigned short*)(base + 6 * MiB);               // 2
    unsigned short* w2_t   = (unsigned short*)(base + 8 * MiB);               // 2
    unsigned short* qbuf   = (unsigned short*)(base + 10 * MiB);              // 4
    unsigned short* kbuf   = (unsigned short*)(base + 14 * MiB);              // 4
    unsigned short* vtbuf  = (unsigned short*)(base + 18 * MiB);              // 4
    unsigned short* o_b    = (unsigned short*)(base + 22 * MiB);              // 4
    unsigned short* pOut   = (unsigned short*)(base + 26 * MiB);              // 8  (2 partials)
    unsigned short* x1b    = (unsigned short*)(base + 34 * MiB);              // 4
    unsigned short* ff1b   = (unsigned short*)(base + 38 * MiB);              // 16
    unsigned short* pFF2   = (unsigned short*)(base + 54 * MiB);              // 16 (4 partials)

    // 0) conversions + weight transposes (one kernel)
    prep<<<4096, 256, 0, stream>>>(x, xb, qkv_w, out_w, w1, w2,
                                   qkvw_t, outw_t, w1_t, w2_t);

    // 1) qkv projection -> qb/kb/vtb (2-phase dbuf)
    gemm_qkv<<<dim3(3 * D / 128, SEQ / 128), 256, 0, stream>>>(
        xb, qkvw_t, qkv_b, qbuf, kbuf, vtbuf);

    // 2) MFMA windowed attention -> o bf16
    attn_mfma<<<dim3(SEQ / 64, NH), 256, 0, stream>>>(qbuf, kbuf, vtbuf, o_b);

    // 3) out-proj, split-K 2 -> bf16 partials
    gemm_splitk<<<dim3(D / 128, SEQ / 128, 2), 256, 0, stream>>>(
        o_b, outw_t, out_b, pOut, SEQ, D, D, D / 2);

    // 4) x1b = bf16( LN(x + p0 + p1) )
    add_ln<2, false, true><<<SEQ / 4, 256, 0, stream>>>(
        x, pOut, (size_t)SEQ * D, ln1_g, ln1_b, x1b);

    // 5) ff1 = relu(x1b @ w1 + b1) -> bf16
    gemm_mfma<true, true><<<dim3(DFF / 128, SEQ / 128), 256, 0, stream>>>(
        x1b, w1_t, b1, ff1b, SEQ, DFF, D);

    // 6) ff2 split-K 4 -> bf16 partials
    gemm_splitk<<<dim3(D / 128, SEQ / 128, 4), 256, 0, stream>>>(
        ff1b, w2_t, b2, pFF2, SEQ, D, DFF, DFF / 4);

    // 7) out = LN(x1b + p0+p1+p2+p3) -> fp32
    add_ln<4, true, false><<<SEQ / 4, 256, 0, stream>>>(
        x1b, pFF2, (size_t)SEQ * D, ln2_g, ln2_b, out);
}